// Round 1
// baseline (2048.834 us; speedup 1.0000x reference)
//
#include <hip/hip_runtime.h>
#include <math.h>

// Problem constants
#define BATCH 2
#define CDIM 512
#define NH 8
#define DHEAD 64
#define NPOS 4096          // 64*64
#define KMAX 32

// ws layout (float offsets)
#define WS_Q  0            // [B][8][4096][64] — also reused as attention output O
#define WS_K  4194304
#define WS_V  8388608
#define WS_G1 12582912     // [B][128][4096]
#define WS_KD 13631488     // int [B][4096]

#define XSTRIDE  2097152u  // per-batch stride of x / qkv-buffers / out (512*4096 = 8*4096*64)
#define G1STRIDE 524288u   // per-batch stride of G1

// ---------------------------------------------------------------------------
// Generic 128x128x512 fp32 GEMM: Y[o,n] = sum_c A[o,c] * B[c,n]  (per batch z)
// EPI 0: qkv    -> scatter to Q/K/V in [b,h,n,d] layout, q scaled by 0.125
// EPI 1: gate1  -> relu(acc + bias) -> G1[b][o][n]
// EPI 2: proj   -> B operand read from O[b,h,n,d] (transpose-staged);
//                  out = resid + acc + bias -> d_out[b][o][n]
// ---------------------------------------------------------------------------
template<int EPI>
__global__ __launch_bounds__(256)
void gemm_kernel(const float* __restrict__ A, const float* __restrict__ B,
                 const float* __restrict__ bias, const float* __restrict__ resid,
                 float* __restrict__ W0, float* __restrict__ W1, float* __restrict__ W2)
{
    const int tid = threadIdx.x;
    const int tm = tid & 15;        // m-group (8 rows each)
    const int tn = tid >> 4;        // n-group (8 cols each)
    const int m0 = blockIdx.y * 128;
    const int n0 = blockIdx.x * 128;
    const int b  = blockIdx.z;

    const float* Bb = B + (size_t)b * XSTRIDE;

    __shared__ float As[16][132];
    __shared__ float Bs[16][132];

    float acc[8][8];
    #pragma unroll
    for (int i = 0; i < 8; ++i)
        #pragma unroll
        for (int j = 0; j < 8; ++j) acc[i][j] = 0.0f;

    for (int k0 = 0; k0 < 512; k0 += 16) {
        // ---- stage A tile [128 m][16 k] (A row-major [M][512]) ----
        {
            int id = tid * 2;
            #pragma unroll
            for (int r = 0; r < 2; ++r, ++id) {
                int m = id >> 2, kq = (id & 3) * 4;
                float4 v = *(const float4*)(A + (size_t)(m0 + m) * 512 + k0 + kq);
                As[kq + 0][m] = v.x; As[kq + 1][m] = v.y;
                As[kq + 2][m] = v.z; As[kq + 3][m] = v.w;
            }
        }
        // ---- stage B tile [16 k][128 n] ----
        if (EPI != 2) {
            // B is row-major [512][4096]
            int id = tid * 2;
            #pragma unroll
            for (int r = 0; r < 2; ++r, ++id) {
                int kk = id >> 5, nq = (id & 31) * 4;
                *(float4*)(&Bs[kk][nq]) =
                    *(const float4*)(Bb + (size_t)(k0 + kk) * 4096 + n0 + nq);
            }
        } else {
            // B is O in [8][4096][64]; c = k0+k -> h = c>>6, d = c&63 (16-chunk within one head)
            int id = tid * 2;
            const int h = k0 >> 6, d0 = k0 & 63;
            #pragma unroll
            for (int r = 0; r < 2; ++r, ++id) {
                int n = id >> 2, kq = (id & 3) * 4;
                float4 v = *(const float4*)(Bb + ((size_t)(h * 4096) + n0 + n) * 64 + d0 + kq);
                Bs[kq + 0][n] = v.x; Bs[kq + 1][n] = v.y;
                Bs[kq + 2][n] = v.z; Bs[kq + 3][n] = v.w;
            }
        }
        __syncthreads();
        // ---- compute ----
        #pragma unroll
        for (int k = 0; k < 16; ++k) {
            float4 a0 = *(const float4*)(&As[k][tm * 8]);
            float4 a1 = *(const float4*)(&As[k][tm * 8 + 4]);
            float4 b0 = *(const float4*)(&Bs[k][tn * 8]);
            float4 b1 = *(const float4*)(&Bs[k][tn * 8 + 4]);
            float a[8] = {a0.x, a0.y, a0.z, a0.w, a1.x, a1.y, a1.z, a1.w};
            float bb[8] = {b0.x, b0.y, b0.z, b0.w, b1.x, b1.y, b1.z, b1.w};
            #pragma unroll
            for (int i = 0; i < 8; ++i)
                #pragma unroll
                for (int j = 0; j < 8; ++j)
                    acc[i][j] += a[i] * bb[j];
        }
        __syncthreads();
    }

    // ---- epilogue ----
    if (EPI == 0) {
        const int which = m0 >> 9;                 // 0=q 1=k 2=v
        const int mm = (m0 & 511) + tm * 8;        // 8 consecutive d within one head
        const int h = mm >> 6, d0 = mm & 63;
        const float scale = (which == 0) ? 0.125f : 1.0f;
        float* dst = ((which == 0) ? W0 : (which == 1) ? W1 : W2)
                     + ((size_t)(b * 8 + h) * 4096) * 64 + d0;
        #pragma unroll
        for (int j = 0; j < 8; ++j) {
            size_t nn = (size_t)(n0 + tn * 8 + j) * 64;
            float4 v0 = make_float4(acc[0][j] * scale, acc[1][j] * scale,
                                    acc[2][j] * scale, acc[3][j] * scale);
            float4 v1 = make_float4(acc[4][j] * scale, acc[5][j] * scale,
                                    acc[6][j] * scale, acc[7][j] * scale);
            *(float4*)(dst + nn) = v0;
            *(float4*)(dst + nn + 4) = v1;
        }
    } else if (EPI == 1) {
        #pragma unroll
        for (int i = 0; i < 8; ++i) {
            int o = tm * 8 + i;
            float bi = bias[o];
            float* dst = W0 + (size_t)b * G1STRIDE + (size_t)o * 4096 + n0 + tn * 8;
            float v[8];
            #pragma unroll
            for (int j = 0; j < 8; ++j) v[j] = fmaxf(acc[i][j] + bi, 0.0f);
            *(float4*)(dst) = make_float4(v[0], v[1], v[2], v[3]);
            *(float4*)(dst + 4) = make_float4(v[4], v[5], v[6], v[7]);
        }
    } else {
        #pragma unroll
        for (int i = 0; i < 8; ++i) {
            int o = m0 + tm * 8 + i;
            float bi = bias[o];
            size_t off = (size_t)b * XSTRIDE + (size_t)o * 4096 + n0 + tn * 8;
            float4 r0 = *(const float4*)(resid + off);
            float4 r1 = *(const float4*)(resid + off + 4);
            float4 v0 = make_float4(acc[i][0] + bi + r0.x, acc[i][1] + bi + r0.y,
                                    acc[i][2] + bi + r0.z, acc[i][3] + bi + r0.w);
            float4 v1 = make_float4(acc[i][4] + bi + r1.x, acc[i][5] + bi + r1.y,
                                    acc[i][6] + bi + r1.z, acc[i][7] + bi + r1.w);
            *(float4*)(W0 + off) = v0;
            *(float4*)(W0 + off + 4) = v1;
        }
    }
}

// ---------------------------------------------------------------------------
// gate2: tau = sigmoid(w2 . g1 + b2); k_dyn = clip(trunc(tau*32), 4, 32)
// one wave per 64 positions; G1 column reads are coalesced over n.
// ---------------------------------------------------------------------------
__global__ __launch_bounds__(64)
void gate2_kernel(const float* __restrict__ G1, const float* __restrict__ w2,
                  const float* __restrict__ b2, int* __restrict__ KD)
{
    const int b = blockIdx.y;
    const int n = blockIdx.x * 64 + threadIdx.x;
    const float* g = G1 + (size_t)b * G1STRIDE + n;
    float z = b2[0];
    #pragma unroll 8
    for (int c = 0; c < 128; ++c) z += w2[c] * g[(size_t)c * 4096];
    float tau = 1.0f / (1.0f + expf(-z));
    int kd = (int)(tau * 32.0f);
    kd = min(32, max(4, kd));
    KD[b * 4096 + n] = kd;
}

// ---------------------------------------------------------------------------
// Fused QK^T + streaming top-k_dyn + softmax + V-gather.
// Block: 256 thr (4 waves), 64 query rows (16/wave), loop over 64 key tiles.
// Per-row state: top-k_dyn (val,idx) held in lanes 0..31 registers,
// min-replacement with strict > (matches jax top_k earliest-index ties).
// ---------------------------------------------------------------------------
__device__ inline float wave_min_f(float v) {
    #pragma unroll
    for (int m = 32; m >= 1; m >>= 1) v = fminf(v, __shfl_xor(v, m));
    return v;
}
__device__ inline float wave_max_f(float v) {
    #pragma unroll
    for (int m = 32; m >= 1; m >>= 1) v = fmaxf(v, __shfl_xor(v, m));
    return v;
}
__device__ inline float wave_sum_f(float v) {
    #pragma unroll
    for (int m = 32; m >= 1; m >>= 1) v += __shfl_xor(v, m);
    return v;
}

__global__ __launch_bounds__(256)
void attn_kernel(const float* __restrict__ Q, const float* __restrict__ Kb,
                 const float* __restrict__ V, const int* __restrict__ KD,
                 float* __restrict__ O)
{
    const int qt = blockIdx.x;       // query tile (64 rows)
    const int h  = blockIdx.y;
    const int b  = blockIdx.z;
    const size_t base = (size_t)(b * 8 + h) * 4096 * 64;
    const int i0 = qt * 64;

    __shared__ float Qs[64][68];
    __shared__ float Ks[64][68];
    __shared__ float Ssl[4][16][68];   // per-wave score rows

    const int tid = threadIdx.x;
    const int lane = tid & 63;
    const int w = tid >> 6;
    const int tj = tid & 15;
    const int tig = tid >> 4;          // 0..15 (wave w owns tig in [4w,4w+3])

    // stage Q tile (q pre-scaled by 1/8 in the qkv GEMM)
    #pragma unroll
    for (int r = 0; r < 4; ++r) {
        int lin = r * 1024 + tid * 4;
        int i = lin >> 6, dq = lin & 63;
        *(float4*)(&Qs[i][dq]) = *(const float4*)(Q + base + (size_t)(i0 + i) * 64 + dq);
    }

    // per-row top-k state (16 rows per wave, state across lanes 0..kd-1)
    float sv[16], cmin[16];
    int si[16], kdr[16];
    const float INF = __builtin_inff();
    #pragma unroll
    for (int i = 0; i < 16; ++i) {
        kdr[i] = KD[b * 4096 + i0 + 16 * w + i];
        sv[i] = (lane < kdr[i]) ? -INF : INF;
        si[i] = 0;
        cmin[i] = -INF;
    }

    for (int t = 0; t < 64; ++t) {
        const int j0 = t * 64;
        __syncthreads();               // prev iter's Ks readers done
        #pragma unroll
        for (int r = 0; r < 4; ++r) {
            int lin = r * 1024 + tid * 4;
            int j = lin >> 6, dq = lin & 63;
            *(float4*)(&Ks[j][dq]) = *(const float4*)(Kb + base + (size_t)(j0 + j) * 64 + dq);
        }
        __syncthreads();

        // S tile: rows 4*tig..4*tig+3, cols tj+16*jj
        float acc[4][4];
        #pragma unroll
        for (int ii = 0; ii < 4; ++ii)
            #pragma unroll
            for (int jj = 0; jj < 4; ++jj) acc[ii][jj] = 0.0f;
        #pragma unroll
        for (int dq = 0; dq < 64; dq += 4) {
            float4 qv[4], kv[4];
            #pragma unroll
            for (int ii = 0; ii < 4; ++ii) qv[ii] = *(const float4*)(&Qs[4 * tig + ii][dq]);
            #pragma unroll
            for (int jj = 0; jj < 4; ++jj) kv[jj] = *(const float4*)(&Ks[tj + 16 * jj][dq]);
            #pragma unroll
            for (int ii = 0; ii < 4; ++ii)
                #pragma unroll
                for (int jj = 0; jj < 4; ++jj) {
                    acc[ii][jj] += qv[ii].x * kv[jj].x;
                    acc[ii][jj] += qv[ii].y * kv[jj].y;
                    acc[ii][jj] += qv[ii].z * kv[jj].z;
                    acc[ii][jj] += qv[ii].w * kv[jj].w;
                }
        }
        // park scores in own wave's LDS region, laned by j
        {
            const int tiw = tig & 3;
            #pragma unroll
            for (int ii = 0; ii < 4; ++ii)
                #pragma unroll
                for (int jj = 0; jj < 4; ++jj)
                    Ssl[w][4 * tiw + ii][tj + 16 * jj] = acc[ii][jj];
        }
        __syncthreads();

        // streaming top-k merge, rows in order, candidates in j order
        #pragma unroll
        for (int i = 0; i < 16; ++i) {
            float c = Ssl[w][i][lane];
            unsigned long long m = __ballot(c > cmin[i]);
            while (m) {
                int L = __ffsll(m) - 1;
                m &= m - 1;
                float cv = __shfl(c, L);
                if (cv > cmin[i]) {
                    unsigned long long eq = __ballot(sv[i] == cmin[i]);
                    int F = __ffsll(eq) - 1;
                    if (lane == F) { sv[i] = cv; si[i] = j0 + L; }
                    cmin[i] = wave_min_f(sv[i]);
                }
            }
        }
    }

    // softmax over the selected set + V gather (lane = d)
    #pragma unroll
    for (int i = 0; i < 16; ++i) {
        const int row = i0 + 16 * w + i;
        const int kd = kdr[i];
        float vkeep = (lane < kd) ? sv[i] : -INF;
        float mx = wave_max_f(vkeep);
        float e = (lane < kd) ? expf(sv[i] - mx) : 0.0f;
        float s = wave_sum_f(e);
        float wgt = e / s;
        float o = 0.0f;
        for (int kk = 0; kk < kd; ++kk) {
            float wk = __shfl(wgt, kk);
            int ik = __shfl(si[i], kk);
            o += wk * V[base + (size_t)ik * 64 + lane];
        }
        O[base + (size_t)row * 64 + lane] = o;
    }
}

// ---------------------------------------------------------------------------
extern "C" void kernel_launch(void* const* d_in, const int* in_sizes, int n_in,
                              void* d_out, int out_size, void* d_ws, size_t ws_size,
                              hipStream_t stream)
{
    const float* x      = (const float*)d_in[0];
    const float* w_qkv  = (const float*)d_in[1];
    const float* w_proj = (const float*)d_in[2];
    const float* b_proj = (const float*)d_in[3];
    const float* w_g1   = (const float*)d_in[4];
    const float* b_g1   = (const float*)d_in[5];
    const float* w_g2   = (const float*)d_in[6];
    const float* b_g2   = (const float*)d_in[7];
    float* out = (float*)d_out;
    float* ws  = (float*)d_ws;

    float* Qb = ws + WS_Q;           // also attention output O (safe aliasing:
    float* Kb = ws + WS_K;           // each block reads its Q rows before writing them)
    float* Vb = ws + WS_V;
    float* G1 = ws + WS_G1;
    int*   KD = (int*)(ws + WS_KD);

    // qkv projection -> Q(x0.125)/K/V in [b,h,n,d]
    gemm_kernel<0><<<dim3(32, 12, 2), 256, 0, stream>>>(w_qkv, x, nullptr, nullptr, Qb, Kb, Vb);
    // gate conv1 (bias+relu)
    gemm_kernel<1><<<dim3(32, 1, 2), 256, 0, stream>>>(w_g1, x, b_g1, nullptr, G1, nullptr, nullptr);
    // gate conv2 -> k_dyn
    gate2_kernel<<<dim3(64, 2), 64, 0, stream>>>(G1, w_g2, b_g2, KD);
    // fused attention (writes O into Q buffer)
    attn_kernel<<<dim3(64, 8, 2), 256, 0, stream>>>(Qb, Kb, Vb, KD, Qb);
    // output projection + bias + residual
    gemm_kernel<2><<<dim3(32, 4, 2), 256, 0, stream>>>(w_proj, Qb, b_proj, x, out, nullptr, nullptr);
}

// Round 3
// 1377.875 us; speedup vs baseline: 1.4870x; 1.4870x over previous
//
#include <hip/hip_runtime.h>
#include <math.h>

// Problem constants: B=2, C=512, H=8 heads, dh=64, N=4096, Kmax=32
#define XSTRIDE  2097152u  // 512*4096 per-batch stride of x / out
#define G1STRIDE 524288u   // 128*4096

typedef _Float16 f16;
typedef f16   f16x8  __attribute__((ext_vector_type(8)));
typedef float f32x16 __attribute__((ext_vector_type(16)));

// ws layout (float offsets). O overlays QH/QL row-for-row (the attn block that
// writes O rows [i0,i0+64) is the same block that read QH/QL rows [i0,i0+64)
// at kernel start, so no cross-block race).
#define WS_QH 0u          // f16 [2][8][4096][64]  (2,097,152 float-slots)
#define WS_QL 2097152u    // f16 lo parts, pre-scaled x4096
#define WS_KH 4194304u
#define WS_KL 6291456u
#define WS_VB 8388608u    // f16 V
#define WS_G1 10485760u   // f32 [2][128][4096]
#define WS_KD 11534336u   // int [2][4096]

__device__ inline float wave_max_f(float v) {
    #pragma unroll
    for (int m = 32; m >= 1; m >>= 1) v = fmaxf(v, __shfl_xor(v, m));
    return v;
}
__device__ inline float wave_sum_f(float v) {
    #pragma unroll
    for (int m = 32; m >= 1; m >>= 1) v += __shfl_xor(v, m);
    return v;
}

// ---------------------------------------------------------------------------
// 128x128x512 fp32 GEMM: Y[o,n] = sum_c A[o,c] * B[c,n] (per batch z).
// EPI 0: qkv -> Q scaled 0.125, split to f16 hi/lo (P0,P1), lo pre-scaled
//        x4096 (keeps lo parts out of fp16-subnormal range for MFMA);
//        K split (P2,P3); V f16 (P4); all in [b,h,n,d].
// EPI 1: gate1 -> relu(acc+bias) -> G1 (P0)
// EPI 2: proj  -> B operand from O halves (P1,P2); out+bias+resid -> P0
// ---------------------------------------------------------------------------
template<int EPI>
__global__ __launch_bounds__(256)
void gemm_kernel(const float* __restrict__ A, const float* __restrict__ B,
                 const float* __restrict__ bias, const float* __restrict__ resid,
                 void* P0, void* P1, void* P2, void* P3, void* P4)
{
    const int tid = threadIdx.x;
    const int tm = tid & 15;
    const int tn = tid >> 4;
    const int m0 = blockIdx.y * 128;
    const int n0 = blockIdx.x * 128;
    const int b  = blockIdx.z;

    const float* Bb = B + (size_t)b * XSTRIDE;

    __shared__ float As[16][132];
    __shared__ float Bs[16][132];

    float acc[8][8];
    #pragma unroll
    for (int i = 0; i < 8; ++i)
        #pragma unroll
        for (int j = 0; j < 8; ++j) acc[i][j] = 0.0f;

    for (int k0 = 0; k0 < 512; k0 += 16) {
        {   // A tile [128 m][16 k], A row-major [M][512]
            int id = tid * 2;
            #pragma unroll
            for (int r = 0; r < 2; ++r, ++id) {
                int m = id >> 2, kq = (id & 3) * 4;
                float4 v = *(const float4*)(A + (size_t)(m0 + m) * 512 + k0 + kq);
                As[kq + 0][m] = v.x; As[kq + 1][m] = v.y;
                As[kq + 2][m] = v.z; As[kq + 3][m] = v.w;
            }
        }
        if (EPI != 2) {   // B row-major [512][4096]
            int id = tid * 2;
            #pragma unroll
            for (int r = 0; r < 2; ++r, ++id) {
                int kk = id >> 5, nq = (id & 31) * 4;
                *(float4*)(&Bs[kk][nq]) =
                    *(const float4*)(Bb + (size_t)(k0 + kk) * 4096 + n0 + nq);
            }
        } else {          // B from O halves: c=k0+k -> h=c>>6, d=c&63
            const float* O0p = (const float*)P1;
            const float* O1p = (const float*)P2;
            const int hh = k0 >> 6, d0 = k0 & 63;
            int id = tid * 2;
            #pragma unroll
            for (int r = 0; r < 2; ++r, ++id) {
                int n = id >> 2, kq = (id & 3) * 4;
                int dd = d0 + kq;
                size_t rowp = ((size_t)((b * 8 + hh) * 4096) + n0 + n) * 32;
                const float* src = (dd < 32) ? (O0p + rowp + dd) : (O1p + rowp + dd - 32);
                float4 v = *(const float4*)src;
                Bs[kq + 0][n] = v.x; Bs[kq + 1][n] = v.y;
                Bs[kq + 2][n] = v.z; Bs[kq + 3][n] = v.w;
            }
        }
        __syncthreads();
        #pragma unroll
        for (int k = 0; k < 16; ++k) {
            float4 a0 = *(const float4*)(&As[k][tm * 8]);
            float4 a1 = *(const float4*)(&As[k][tm * 8 + 4]);
            float4 b0 = *(const float4*)(&Bs[k][tn * 8]);
            float4 b1 = *(const float4*)(&Bs[k][tn * 8 + 4]);
            float a[8] = {a0.x, a0.y, a0.z, a0.w, a1.x, a1.y, a1.z, a1.w};
            float bb[8] = {b0.x, b0.y, b0.z, b0.w, b1.x, b1.y, b1.z, b1.w};
            #pragma unroll
            for (int i = 0; i < 8; ++i)
                #pragma unroll
                for (int j = 0; j < 8; ++j)
                    acc[i][j] += a[i] * bb[j];
        }
        __syncthreads();
    }

    if (EPI == 0) {
        const int which = m0 >> 9;              // 0=q 1=k 2=v
        const int mm = (m0 & 511) + tm * 8;     // channel within 512
        const int hh = mm >> 6, d0 = mm & 63;   // head, d-octet base
        const size_t rowbase = (size_t)((b * 8 + hh) * 4096);
        if (which == 2) {
            f16* VB = (f16*)P4;
            #pragma unroll
            for (int j = 0; j < 8; ++j) {
                int n = n0 + tn * 8 + j;
                f16x8 v;
                #pragma unroll
                for (int i = 0; i < 8; ++i) v[i] = (f16)acc[i][j];
                *(f16x8*)(VB + (rowbase + n) * 64 + d0) = v;
            }
        } else {
            f16* DH = (f16*)(which ? P2 : P0);
            f16* DL = (f16*)(which ? P3 : P1);
            const float scale = which ? 1.0f : 0.125f;   // q pre-scaled 1/sqrt(64)
            #pragma unroll
            for (int j = 0; j < 8; ++j) {
                int n = n0 + tn * 8 + j;
                f16x8 vh, vl;
                #pragma unroll
                for (int i = 0; i < 8; ++i) {
                    float xx = acc[i][j] * scale;
                    f16 hs = (f16)xx;
                    vh[i] = hs;
                    vl[i] = (f16)((xx - (float)hs) * 4096.0f);  // exact pow2 scale
                }
                *(f16x8*)(DH + (rowbase + n) * 64 + d0) = vh;
                *(f16x8*)(DL + (rowbase + n) * 64 + d0) = vl;
            }
        }
    } else if (EPI == 1) {
        float* G1 = (float*)P0;
        #pragma unroll
        for (int i = 0; i < 8; ++i) {
            int o = tm * 8 + i;
            float bi = bias[o];
            float* dst = G1 + (size_t)b * G1STRIDE + (size_t)o * 4096 + n0 + tn * 8;
            float v[8];
            #pragma unroll
            for (int j = 0; j < 8; ++j) v[j] = fmaxf(acc[i][j] + bi, 0.0f);
            *(float4*)(dst) = make_float4(v[0], v[1], v[2], v[3]);
            *(float4*)(dst + 4) = make_float4(v[4], v[5], v[6], v[7]);
        }
    } else {
        float* out = (float*)P0;
        #pragma unroll
        for (int i = 0; i < 8; ++i) {
            int o = m0 + tm * 8 + i;
            float bi = bias[o];
            size_t off = (size_t)b * XSTRIDE + (size_t)o * 4096 + n0 + tn * 8;
            float4 r0 = *(const float4*)(resid + off);
            float4 r1 = *(const float4*)(resid + off + 4);
            *(float4*)(out + off) = make_float4(acc[i][0] + bi + r0.x, acc[i][1] + bi + r0.y,
                                                acc[i][2] + bi + r0.z, acc[i][3] + bi + r0.w);
            *(float4*)(out + off + 4) = make_float4(acc[i][4] + bi + r1.x, acc[i][5] + bi + r1.y,
                                                    acc[i][6] + bi + r1.z, acc[i][7] + bi + r1.w);
        }
    }
}

// ---------------------------------------------------------------------------
// gate2 (exact fp32 path from R1 — trunc(tau*32) is a discrete decision,
// do not perturb).
// ---------------------------------------------------------------------------
__global__ __launch_bounds__(64)
void gate2_kernel(const float* __restrict__ G1, const float* __restrict__ w2,
                  const float* __restrict__ b2, int* __restrict__ KD)
{
    const int b = blockIdx.y;
    const int n = blockIdx.x * 64 + threadIdx.x;
    const float* g = G1 + (size_t)b * G1STRIDE + n;
    float z = b2[0];
    #pragma unroll 8
    for (int c = 0; c < 128; ++c) z += w2[c] * g[(size_t)c * 4096];
    float tau = 1.0f / (1.0f + expf(-z));
    int kd = (int)(tau * 32.0f);
    kd = min(32, max(4, kd));
    KD[b * 4096 + n] = kd;
}

// ---------------------------------------------------------------------------
// Fused QK^T (fp16x2-split MFMA, 3 passes ~ fp32 precision; lo passes in a
// separate accumulator, combined /4096) + streaming top-k_dyn (sorted
// lane-list insert) + softmax + f16-V gather.
// Block: 256 thr / 4 waves; 64 query rows; 64 key tiles of 64.
// Wave w computes S quadrant rows 32*(w>>1), cols 32*(w&1) via
// v_mfma_f32_32x32x16_f16; merges rows [16w,16w+16).
// ---------------------------------------------------------------------------
__global__ __launch_bounds__(256)
void attn_kernel(const f16* __restrict__ QH, const f16* __restrict__ QL,
                 const f16* __restrict__ KH, const f16* __restrict__ KL,
                 const f16* __restrict__ VB, const int* __restrict__ KD,
                 float* __restrict__ O0, float* __restrict__ O1)
{
    const int qt = blockIdx.x, h = blockIdx.y, b = blockIdx.z;
    const size_t base = (size_t)((b * 8 + h) * 4096) * 64;
    const int i0 = qt * 64;
    const int tid = threadIdx.x, lane = tid & 63, w = tid >> 6;
    const int r0 = (w >> 1) * 32, c0 = (w & 1) * 32;
    const int ln = lane & 31, g = lane >> 5;

    __shared__ f16 Ksh[64][72];   // +8 pad: rows 144B (16B-aligned stores, uniform banks)
    __shared__ f16 Ksl[64][72];
    __shared__ float Ss[64][68];

    // A-operand (Q) frags, loaded once directly from global.
    // 32x32x16 f16 A layout: A[m=lane&31][k=(lane>>5)*8 + j]
    f16x8 ah[4], al[4];
    {
        const f16* ph = QH + base + (size_t)(i0 + r0 + ln) * 64 + g * 8;
        const f16* pl = QL + base + (size_t)(i0 + r0 + ln) * 64 + g * 8;
        #pragma unroll
        for (int s = 0; s < 4; ++s) {
            ah[s] = *(const f16x8*)(ph + s * 16);
            al[s] = *(const f16x8*)(pl + s * 16);
        }
    }

    // Sorted-descending top list across lanes (all 64 lanes, -inf tail);
    // only lanes < kd matter. cmin = sv@lane(kd-1). Strict > keeps
    // earliest-index on ties (jax top_k semantics).
    const float INF = __builtin_inff();
    float sv[16], cmin[16];
    int si[16], kdr[16];
    #pragma unroll
    for (int i = 0; i < 16; ++i) {
        kdr[i] = KD[b * 4096 + i0 + 16 * w + i];
        sv[i] = -INF; cmin[i] = -INF; si[i] = 0;
    }

    for (int t = 0; t < 64; ++t) {
        const int j0 = t * 64;
        __syncthreads();                       // prev tile's Ss/Ks readers done
        #pragma unroll
        for (int r = 0; r < 2; ++r) {
            int id = tid + r * 256;
            int row = id >> 3, oct = id & 7;
            *(f16x8*)(&Ksh[row][oct * 8]) =
                *(const f16x8*)(KH + base + (size_t)(j0 + row) * 64 + oct * 8);
            *(f16x8*)(&Ksl[row][oct * 8]) =
                *(const f16x8*)(KL + base + (size_t)(j0 + row) * 64 + oct * 8);
        }
        __syncthreads();

        f32x16 acc, accL;
        #pragma unroll
        for (int r = 0; r < 16; ++r) { acc[r] = 0.0f; accL[r] = 0.0f; }
        #pragma unroll
        for (int s = 0; s < 4; ++s) {
            // B layout: B[k=(lane>>5)*8+j][n=lane&31]; K^T so B[d][key]=K[key][d]
            f16x8 bh = *(const f16x8*)(&Ksh[c0 + ln][s * 16 + g * 8]);
            f16x8 bl = *(const f16x8*)(&Ksl[c0 + ln][s * 16 + g * 8]);
            acc  = __builtin_amdgcn_mfma_f32_32x32x16_f16(ah[s], bh, acc,  0, 0, 0);
            accL = __builtin_amdgcn_mfma_f32_32x32x16_f16(al[s], bh, accL, 0, 0, 0);
            accL = __builtin_amdgcn_mfma_f32_32x32x16_f16(ah[s], bl, accL, 0, 0, 0);
        }
        // C/D layout (verified m74/m101): col=lane&31, row=(r&3)+8*(r>>2)+4*(lane>>5)
        #pragma unroll
        for (int r = 0; r < 16; ++r)
            Ss[r0 + (r & 3) + 8 * (r >> 2) + 4 * g][c0 + ln] =
                acc[r] + accL[r] * (1.0f / 4096.0f);
        __syncthreads();

        #pragma unroll
        for (int i = 0; i < 16; ++i) {
            float c = Ss[16 * w + i][lane];
            unsigned long long m = __ballot(c > cmin[i]);
            while (m) {
                int L = __ffsll(m) - 1;
                m &= m - 1;
                float cv = __shfl(c, L);
                if (cv > cmin[i]) {            // re-check: cmin moves
                    int pos = __popcll(__ballot(sv[i] >= cv));  // after equals
                    float usv = __shfl_up(sv[i], 1);
                    int   usi = __shfl_up(si[i], 1);
                    if (lane == pos)     { sv[i] = cv;  si[i] = j0 + L; }
                    else if (lane > pos) { sv[i] = usv; si[i] = usi; }
                    cmin[i] = __shfl(sv[i], kdr[i] - 1);
                }
            }
        }
    }

    // softmax over selected set + V gather (lane = d)
    #pragma unroll
    for (int i = 0; i < 16; ++i) {
        const int row = i0 + 16 * w + i;
        const int kd = kdr[i];
        float sval = (lane < kd) ? sv[i] : -INF;
        float mx = wave_max_f(sval);
        float e = (lane < kd) ? expf(sv[i] - mx) : 0.0f;
        float ssum = wave_sum_f(e);
        float wgt = e / ssum;
        float o = 0.0f;
        for (int kk = 0; kk < kd; ++kk) {
            float wk = __shfl(wgt, kk);
            int ik = __shfl(si[i], kk);
            o += wk * (float)VB[base + (size_t)ik * 64 + lane];
        }
        size_t rp = (size_t)((b * 8 + h) * 4096 + row) * 32;
        if (lane < 32) O0[rp + lane] = o;
        else           O1[rp + lane - 32] = o;
    }
}

// ---------------------------------------------------------------------------
extern "C" void kernel_launch(void* const* d_in, const int* in_sizes, int n_in,
                              void* d_out, int out_size, void* d_ws, size_t ws_size,
                              hipStream_t stream)
{
    const float* x      = (const float*)d_in[0];
    const float* w_qkv  = (const float*)d_in[1];
    const float* w_proj = (const float*)d_in[2];
    const float* b_proj = (const float*)d_in[3];
    const float* w_g1   = (const float*)d_in[4];
    const float* b_g1   = (const float*)d_in[5];
    const float* w_g2   = (const float*)d_in[6];
    const float* b_g2   = (const float*)d_in[7];
    float* out = (float*)d_out;
    float* ws  = (float*)d_ws;

    f16* QH = (f16*)(ws + WS_QH);
    f16* QL = (f16*)(ws + WS_QL);
    f16* KH = (f16*)(ws + WS_KH);
    f16* KL = (f16*)(ws + WS_KL);
    f16* VB = (f16*)(ws + WS_VB);
    float* G1 = ws + WS_G1;
    int*   KD = (int*)(ws + WS_KD);
    float* O0 = (float*)QH;   // overlay: attn O replaces Q hi/lo row-for-row
    float* O1 = (float*)QL;

    gemm_kernel<0><<<dim3(32, 12, 2), 256, 0, stream>>>(
        w_qkv, x, nullptr, nullptr, QH, QL, KH, KL, VB);
    gemm_kernel<1><<<dim3(32, 1, 2), 256, 0, stream>>>(
        w_g1, x, b_g1, nullptr, G1, nullptr, nullptr, nullptr, nullptr);
    gate2_kernel<<<dim3(64, 2), 64, 0, stream>>>(G1, w_g2, b_g2, KD);
    attn_kernel<<<dim3(64, 8, 2), 256, 0, stream>>>(QH, QL, KH, KL, VB, KD, O0, O1);
    gemm_kernel<2><<<dim3(32, 4, 2), 256, 0, stream>>>(
        w_proj, nullptr, b_proj, x, out, O0, O1, nullptr, nullptr);
}

// Round 4
// 1263.251 us; speedup vs baseline: 1.6219x; 1.0907x over previous
//
#include <hip/hip_runtime.h>
#include <math.h>

// Problem constants: B=2, C=512, H=8 heads, dh=64, N=4096, Kmax=32
#define XSTRIDE  2097152u  // 512*4096 per-batch stride of x / out
#define G1STRIDE 524288u   // 128*4096

typedef _Float16 f16;
typedef f16   f16x8  __attribute__((ext_vector_type(8)));
typedef float f32x16 __attribute__((ext_vector_type(16)));
typedef unsigned long long u64;

// ws layout (float offsets), same as R3.
#define WS_QH 0u          // f16 [2][8][4096][64]
#define WS_QL 2097152u    // f16 lo parts, pre-scaled x4096
#define WS_KH 4194304u
#define WS_KL 6291456u
#define WS_VB 8388608u    // f16 V
#define WS_G1 10485760u   // f32 [2][128][4096]
#define WS_KD 11534336u   // int [2][4096]

// ---------------------------------------------------------------------------
// 128x128x512 fp32 GEMM (unchanged from R3 — passed; next-round target).
// ---------------------------------------------------------------------------
template<int EPI>
__global__ __launch_bounds__(256)
void gemm_kernel(const float* __restrict__ A, const float* __restrict__ B,
                 const float* __restrict__ bias, const float* __restrict__ resid,
                 void* P0, void* P1, void* P2, void* P3, void* P4)
{
    const int tid = threadIdx.x;
    const int tm = tid & 15;
    const int tn = tid >> 4;
    const int m0 = blockIdx.y * 128;
    const int n0 = blockIdx.x * 128;
    const int b  = blockIdx.z;

    const float* Bb = B + (size_t)b * XSTRIDE;

    __shared__ float As[16][132];
    __shared__ float Bs[16][132];

    float acc[8][8];
    #pragma unroll
    for (int i = 0; i < 8; ++i)
        #pragma unroll
        for (int j = 0; j < 8; ++j) acc[i][j] = 0.0f;

    for (int k0 = 0; k0 < 512; k0 += 16) {
        {   // A tile [128 m][16 k], A row-major [M][512]
            int id = tid * 2;
            #pragma unroll
            for (int r = 0; r < 2; ++r, ++id) {
                int m = id >> 2, kq = (id & 3) * 4;
                float4 v = *(const float4*)(A + (size_t)(m0 + m) * 512 + k0 + kq);
                As[kq + 0][m] = v.x; As[kq + 1][m] = v.y;
                As[kq + 2][m] = v.z; As[kq + 3][m] = v.w;
            }
        }
        if (EPI != 2) {   // B row-major [512][4096]
            int id = tid * 2;
            #pragma unroll
            for (int r = 0; r < 2; ++r, ++id) {
                int kk = id >> 5, nq = (id & 31) * 4;
                *(float4*)(&Bs[kk][nq]) =
                    *(const float4*)(Bb + (size_t)(k0 + kk) * 4096 + n0 + nq);
            }
        } else {          // B from O halves: c=k0+k -> h=c>>6, d=c&63
            const float* O0p = (const float*)P1;
            const float* O1p = (const float*)P2;
            const int hh = k0 >> 6, d0 = k0 & 63;
            int id = tid * 2;
            #pragma unroll
            for (int r = 0; r < 2; ++r, ++id) {
                int n = id >> 2, kq = (id & 3) * 4;
                int dd = d0 + kq;
                size_t rowp = ((size_t)((b * 8 + hh) * 4096) + n0 + n) * 32;
                const float* src = (dd < 32) ? (O0p + rowp + dd) : (O1p + rowp + dd - 32);
                float4 v = *(const float4*)src;
                Bs[kq + 0][n] = v.x; Bs[kq + 1][n] = v.y;
                Bs[kq + 2][n] = v.z; Bs[kq + 3][n] = v.w;
            }
        }
        __syncthreads();
        #pragma unroll
        for (int k = 0; k < 16; ++k) {
            float4 a0 = *(const float4*)(&As[k][tm * 8]);
            float4 a1 = *(const float4*)(&As[k][tm * 8 + 4]);
            float4 b0 = *(const float4*)(&Bs[k][tn * 8]);
            float4 b1 = *(const float4*)(&Bs[k][tn * 8 + 4]);
            float a[8] = {a0.x, a0.y, a0.z, a0.w, a1.x, a1.y, a1.z, a1.w};
            float bb[8] = {b0.x, b0.y, b0.z, b0.w, b1.x, b1.y, b1.z, b1.w};
            #pragma unroll
            for (int i = 0; i < 8; ++i)
                #pragma unroll
                for (int j = 0; j < 8; ++j)
                    acc[i][j] += a[i] * bb[j];
        }
        __syncthreads();
    }

    if (EPI == 0) {
        const int which = m0 >> 9;              // 0=q 1=k 2=v
        const int mm = (m0 & 511) + tm * 8;
        const int hh = mm >> 6, d0 = mm & 63;
        const size_t rowbase = (size_t)((b * 8 + hh) * 4096);
        if (which == 2) {
            f16* VB = (f16*)P4;
            #pragma unroll
            for (int j = 0; j < 8; ++j) {
                int n = n0 + tn * 8 + j;
                f16x8 v;
                #pragma unroll
                for (int i = 0; i < 8; ++i) v[i] = (f16)acc[i][j];
                *(f16x8*)(VB + (rowbase + n) * 64 + d0) = v;
            }
        } else {
            f16* DH = (f16*)(which ? P2 : P0);
            f16* DL = (f16*)(which ? P3 : P1);
            const float scale = which ? 1.0f : 0.125f;
            #pragma unroll
            for (int j = 0; j < 8; ++j) {
                int n = n0 + tn * 8 + j;
                f16x8 vh, vl;
                #pragma unroll
                for (int i = 0; i < 8; ++i) {
                    float xx = acc[i][j] * scale;
                    f16 hs = (f16)xx;
                    vh[i] = hs;
                    vl[i] = (f16)((xx - (float)hs) * 4096.0f);
                }
                *(f16x8*)(DH + (rowbase + n) * 64 + d0) = vh;
                *(f16x8*)(DL + (rowbase + n) * 64 + d0) = vl;
            }
        }
    } else if (EPI == 1) {
        float* G1 = (float*)P0;
        #pragma unroll
        for (int i = 0; i < 8; ++i) {
            int o = tm * 8 + i;
            float bi = bias[o];
            float* dst = G1 + (size_t)b * G1STRIDE + (size_t)o * 4096 + n0 + tn * 8;
            float v[8];
            #pragma unroll
            for (int j = 0; j < 8; ++j) v[j] = fmaxf(acc[i][j] + bi, 0.0f);
            *(float4*)(dst) = make_float4(v[0], v[1], v[2], v[3]);
            *(float4*)(dst + 4) = make_float4(v[4], v[5], v[6], v[7]);
        }
    } else {
        float* out = (float*)P0;
        #pragma unroll
        for (int i = 0; i < 8; ++i) {
            int o = m0 + tm * 8 + i;
            float bi = bias[o];
            size_t off = (size_t)b * XSTRIDE + (size_t)o * 4096 + n0 + tn * 8;
            float4 r0 = *(const float4*)(resid + off);
            float4 r1 = *(const float4*)(resid + off + 4);
            *(float4*)(out + off) = make_float4(acc[i][0] + bi + r0.x, acc[i][1] + bi + r0.y,
                                                acc[i][2] + bi + r0.z, acc[i][3] + bi + r0.w);
            *(float4*)(out + off + 4) = make_float4(acc[i][4] + bi + r1.x, acc[i][5] + bi + r1.y,
                                                    acc[i][6] + bi + r1.z, acc[i][7] + bi + r1.w);
        }
    }
}

// ---------------------------------------------------------------------------
// gate2 (exact fp32 path — trunc(tau*32) is discrete, do not perturb).
// ---------------------------------------------------------------------------
__global__ __launch_bounds__(64)
void gate2_kernel(const float* __restrict__ G1, const float* __restrict__ w2,
                  const float* __restrict__ b2, int* __restrict__ KD)
{
    const int b = blockIdx.y;
    const int n = blockIdx.x * 64 + threadIdx.x;
    const float* g = G1 + (size_t)b * G1STRIDE + n;
    float z = b2[0];
    #pragma unroll 8
    for (int c = 0; c < 128; ++c) z += w2[c] * g[(size_t)c * 4096];
    float tau = 1.0f / (1.0f + expf(-z));
    int kd = (int)(tau * 32.0f);
    kd = min(32, max(4, kd));
    KD[b * 4096 + n] = kd;
}

// ---------------------------------------------------------------------------
// Fused attention, row-per-thread selection (no cross-lane ops in hot path).
// Block = 256 threads = 4 waves, owns 256 query rows; wave w owns rows
// [w*64, w*64+64), lane l owns row w*64+l. Per 64-key tile:
//   - wave MFMAs its 64x64 score quadrant set (fp16x2 3-pass, same math as R3)
//   - parks fp32 scores in per-wave LDS slab
//   - each lane scans its own row, captures candidates > L[31] into a
//     per-thread LDS FIFO (preserves j-order => jax tie semantics),
//     drains via unrolled 32-step predicated shift-insert (pure VALU).
// Epilogue: per-lane softmax (same order as reference) + per-lane V gather,
// transpose O through LDS for coalesced store.
// ---------------------------------------------------------------------------
__global__ __launch_bounds__(256, 1)
void attn_kernel(const f16* __restrict__ QH, const f16* __restrict__ QL,
                 const f16* __restrict__ KH, const f16* __restrict__ KL,
                 const f16* __restrict__ VB, const int* __restrict__ KD,
                 float* __restrict__ O0, float* __restrict__ O1)
{
    const int qt = blockIdx.x, h = blockIdx.y, b = blockIdx.z;
    const size_t base = (size_t)((b * 8 + h) * 4096) * 64;
    const int tid = threadIdx.x, lane = tid & 63, w = tid >> 6;
    const int ln = lane & 31, g = lane >> 5;
    const int n0 = qt * 256;          // block's first query row
    const int nw = n0 + w * 64;       // wave's first row

    __shared__ float Ss[256 * 68];    // per-wave score slabs [64 rows][68] (b128-aligned stride)
    __shared__ f16   Ksh[64 * 76];    // K tile hi, row stride 76 (bank spread for frag reads)
    __shared__ f16   Ksl[64 * 76];    // K tile lo
    __shared__ u64   Qq[256 * 25];    // per-thread candidate FIFO, 24 usable (stride 25 u64)

    // ---- Q A-frags (resident all kernel): A[m=ln][k=16s+8g+j] ----
    f16x8 ah[2][4], al[2][4];
    #pragma unroll
    for (int rb = 0; rb < 2; ++rb) {
        const f16* ph = QH + base + (size_t)(nw + rb * 32 + ln) * 64 + g * 8;
        const f16* pl = QL + base + (size_t)(nw + rb * 32 + ln) * 64 + g * 8;
        #pragma unroll
        for (int s = 0; s < 4; ++s) {
            ah[rb][s] = *(const f16x8*)(ph + s * 16);
            al[rb][s] = *(const f16x8*)(pl + s * 16);
        }
    }

    const float INF = __builtin_inff();
    float L[32]; int I[32];
    #pragma unroll
    for (int i = 0; i < 32; ++i) { L[i] = -INF; I[i] = 0; }
    int cnt = 0;

    // ---- stage tile 0 (flat: 512 x 16B each of hi/lo; row=flat/8, part=flat%8) ----
    {
        const f16* sh = KH + base;
        const f16* sl = KL + base;
        f16x8 a0 = *(const f16x8*)(sh + (size_t)tid * 8);
        f16x8 a1 = *(const f16x8*)(sh + (size_t)(tid + 256) * 8);
        f16x8 b0v = *(const f16x8*)(sl + (size_t)tid * 8);
        f16x8 b1v = *(const f16x8*)(sl + (size_t)(tid + 256) * 8);
        int row = tid >> 3, part = tid & 7;
        *(f16x8*)(&Ksh[row * 76 + part * 8]) = a0;
        *(f16x8*)(&Ksh[(row + 32) * 76 + part * 8]) = a1;
        *(f16x8*)(&Ksl[row * 76 + part * 8]) = b0v;
        *(f16x8*)(&Ksl[(row + 32) * 76 + part * 8]) = b1v;
    }
    __syncthreads();

    f16x8 pH0, pH1, pL0, pL1;
    for (int t = 0; t < 64; ++t) {
        const int j0 = t * 64;
        // prefetch next tile into registers (latency hidden by compute below)
        if (t < 63) {
            const f16* sh = KH + base + (size_t)(j0 + 64) * 64;
            const f16* sl = KL + base + (size_t)(j0 + 64) * 64;
            pH0 = *(const f16x8*)(sh + (size_t)tid * 8);
            pH1 = *(const f16x8*)(sh + (size_t)(tid + 256) * 8);
            pL0 = *(const f16x8*)(sl + (size_t)tid * 8);
            pL1 = *(const f16x8*)(sl + (size_t)(tid + 256) * 8);
        }

        // ---- MFMA: 4 quadrants (2 cb x 2 rb), fp16x2 3-pass ----
        #pragma unroll
        for (int cb = 0; cb < 2; ++cb) {
            f16x8 bh[4], bl[4];
            #pragma unroll
            for (int s = 0; s < 4; ++s) {
                bh[s] = *(const f16x8*)(&Ksh[(cb * 32 + ln) * 76 + s * 16 + g * 8]);
                bl[s] = *(const f16x8*)(&Ksl[(cb * 32 + ln) * 76 + s * 16 + g * 8]);
            }
            #pragma unroll
            for (int rb = 0; rb < 2; ++rb) {
                f32x16 acc, accL;
                #pragma unroll
                for (int r = 0; r < 16; ++r) { acc[r] = 0.0f; accL[r] = 0.0f; }
                #pragma unroll
                for (int s = 0; s < 4; ++s) {
                    acc  = __builtin_amdgcn_mfma_f32_32x32x16_f16(ah[rb][s], bh[s], acc,  0, 0, 0);
                    accL = __builtin_amdgcn_mfma_f32_32x32x16_f16(al[rb][s], bh[s], accL, 0, 0, 0);
                    accL = __builtin_amdgcn_mfma_f32_32x32x16_f16(ah[rb][s], bl[s], accL, 0, 0, 0);
                }
                // C layout: row=(r&3)+8*(r>>2)+4g, col=ln (verified m74/m101)
                #pragma unroll
                for (int r = 0; r < 16; ++r) {
                    int riw = rb * 32 + (r & 3) + 8 * (r >> 2) + 4 * g;
                    Ss[(w * 64 + riw) * 68 + cb * 32 + ln] = acc[r] + accL[r] * (1.0f / 4096.0f);
                }
            }
        }
        // same-wave LDS ops are in-order: scan below sees the writes, no barrier

        // ---- scan own row, capture > L[31] into FIFO, drain as needed ----
        {
            const int srow = (w * 64 + lane) * 68;
            const int qb = tid * 25;
            #pragma unroll
            for (int ch = 0; ch < 4; ++ch) {
                #pragma unroll
                for (int q = 0; q < 4; ++q) {
                    float4 v = *(const float4*)(&Ss[srow + ch * 16 + q * 4]);
                    int jb = j0 + ch * 16 + q * 4;
                    if (v.x > L[31]) { Qq[qb + cnt] = (u64)__float_as_uint(v.x) | ((u64)(unsigned)(jb + 0) << 32); cnt++; }
                    if (v.y > L[31]) { Qq[qb + cnt] = (u64)__float_as_uint(v.y) | ((u64)(unsigned)(jb + 1) << 32); cnt++; }
                    if (v.z > L[31]) { Qq[qb + cnt] = (u64)__float_as_uint(v.z) | ((u64)(unsigned)(jb + 2) << 32); cnt++; }
                    if (v.w > L[31]) { Qq[qb + cnt] = (u64)__float_as_uint(v.w) | ((u64)(unsigned)(jb + 3) << 32); cnt++; }
                }
                // drain: at tile end always (if any), mid-tile only on overflow risk
                bool need = (ch == 3) ? (__ballot(cnt > 0) != 0ull) : (__ballot(cnt > 8) != 0ull);
                if (need) {
                    for (int p = 0; ; ++p) {
                        if (__ballot(p < cnt) == 0ull) break;
                        float cv = -INF; int cj = 0;
                        if (p < cnt) {
                            u64 pk = Qq[qb + p];
                            cv = __uint_as_float((unsigned)pk);
                            cj = (int)(unsigned)(pk >> 32);
                        }
                        // unrolled sorted-desc shift-insert; cv=-INF is a no-op
                        #pragma unroll
                        for (int r = 31; r >= 1; --r) {
                            bool gp = cv > L[r - 1];
                            bool gc = cv > L[r];
                            L[r] = gp ? L[r - 1] : (gc ? cv : L[r]);
                            I[r] = gp ? I[r - 1] : (gc ? cj : I[r]);
                        }
                        if (cv > L[0]) { L[0] = cv; I[0] = cj; }
                    }
                    cnt = 0;
                }
            }
        }

        __syncthreads();              // all waves done with Ks tile t
        if (t < 63) {
            int row = tid >> 3, part = tid & 7;
            *(f16x8*)(&Ksh[row * 76 + part * 8]) = pH0;
            *(f16x8*)(&Ksh[(row + 32) * 76 + part * 8]) = pH1;
            *(f16x8*)(&Ksl[row * 76 + part * 8]) = pL0;
            *(f16x8*)(&Ksl[(row + 32) * 76 + part * 8]) = pL1;
        }
        __syncthreads();              // Ks tile t+1 ready
    }

    // ---- epilogue: per-lane softmax + V gather ----
    const int myrow = nw + lane;
    const int kd = KD[b * 4096 + myrow];
    float mx = L[0];                  // sorted desc => max first (kd>=4)
    float wsum = 0.0f;
    #pragma unroll
    for (int i = 0; i < 32; ++i) {
        float e = (i < kd) ? expf(L[i] - mx) : 0.0f;   // same order as reference (desc)
        L[i] = e;
        wsum += e;
    }
    const float inv = 1.0f / wsum;

    float o[64];
    #pragma unroll
    for (int d = 0; d < 64; ++d) o[d] = 0.0f;
    for (int i = 0; i < 32; ++i) {
        if (__ballot(i < kd) == 0ull) break;
        float sc = (i < kd) ? L[i] * inv : 0.0f;
        const f16* vp = VB + base + (size_t)(unsigned)I[i] * 64;  // I[i]=0 for inactive: safe addr
        #pragma unroll
        for (int part = 0; part < 8; ++part) {
            f16x8 vv = *(const f16x8*)(vp + part * 8);
            #pragma unroll
            for (int e2 = 0; e2 < 8; ++e2) o[part * 8 + e2] += sc * (float)vv[e2];
        }
    }

    // transpose O through own wave's slab (same-wave LDS, in-order)
    #pragma unroll
    for (int p4 = 0; p4 < 16; ++p4)
        *(float4*)(&Ss[(w * 64 + lane) * 68 + p4 * 4]) =
            make_float4(o[p4 * 4], o[p4 * 4 + 1], o[p4 * 4 + 2], o[p4 * 4 + 3]);
    for (int r = 0; r < 64; ++r) {
        float val = Ss[(w * 64 + r) * 68 + lane];
        size_t gidx = (size_t)((b * 8 + h) * 4096 + nw + r);
        if (lane < 32) O0[gidx * 32 + lane] = val;
        else           O1[gidx * 32 + (lane - 32)] = val;
    }
}

// ---------------------------------------------------------------------------
extern "C" void kernel_launch(void* const* d_in, const int* in_sizes, int n_in,
                              void* d_out, int out_size, void* d_ws, size_t ws_size,
                              hipStream_t stream)
{
    const float* x      = (const float*)d_in[0];
    const float* w_qkv  = (const float*)d_in[1];
    const float* w_proj = (const float*)d_in[2];
    const float* b_proj = (const float*)d_in[3];
    const float* w_g1   = (const float*)d_in[4];
    const float* b_g1   = (const float*)d_in[5];
    const float* w_g2   = (const float*)d_in[6];
    const float* b_g2   = (const float*)d_in[7];
    float* out = (float*)d_out;
    float* ws  = (float*)d_ws;

    f16* QH = (f16*)(ws + WS_QH);
    f16* QL = (f16*)(ws + WS_QL);
    f16* KH = (f16*)(ws + WS_KH);
    f16* KL = (f16*)(ws + WS_KL);
    f16* VB = (f16*)(ws + WS_VB);
    float* G1 = ws + WS_G1;
    int*   KD = (int*)(ws + WS_KD);
    float* O0 = (float*)QH;   // overlay: attn O replaces Q hi/lo row-for-row
    float* O1 = (float*)QL;

    gemm_kernel<0><<<dim3(32, 12, 2), 256, 0, stream>>>(
        w_qkv, x, nullptr, nullptr, QH, QL, KH, KL, VB);
    gemm_kernel<1><<<dim3(32, 1, 2), 256, 0, stream>>>(
        w_g1, x, b_g1, nullptr, G1, nullptr, nullptr, nullptr, nullptr);
    gate2_kernel<<<dim3(64, 2), 64, 0, stream>>>(G1, w_g2, b_g2, KD);
    attn_kernel<<<dim3(16, 8, 2), 256, 0, stream>>>(QH, QL, KH, KL, VB, KD, O0, O1);
    gemm_kernel<2><<<dim3(32, 4, 2), 256, 0, stream>>>(
        w_proj, nullptr, b_proj, x, out, O0, O1, nullptr, nullptr);
}

// Round 7
// 1119.206 us; speedup vs baseline: 1.8306x; 1.1287x over previous
//
#include <hip/hip_runtime.h>
#include <math.h>

// Problem constants: B=2, C=512, H=8 heads, dh=64, N=4096, Kmax=32
#define XSTRIDE  2097152u  // 512*4096 per-batch stride of x / out
#define G1STRIDE 524288u   // 128*4096

typedef _Float16 f16;
typedef f16   f16x8  __attribute__((ext_vector_type(8)));
typedef float f32x16 __attribute__((ext_vector_type(16)));
typedef unsigned int u32;
typedef unsigned short u16;

// ws layout (float offsets). Total 13,639,680 floats = 54.56 MB (== R1's
// proven footprint). CV lives in d_out (4,194,304 floats, exact fit):
// select writes it, merge reads it, proj overwrites d_out afterward.
#define WS_QH 0u          // f16 [2][8][4096][64]
#define WS_QL 2097152u    // f16 lo parts, pre-scaled x4096
#define WS_KH 4194304u
#define WS_KL 6291456u
#define WS_VB 8388608u    // f16 V
#define WS_G1 10485760u   // f32 [2][128][4096]
#define WS_KD 11534336u   // int [2][4096]
#define WS_CI 11542528u   // u16 [65536 rows][64 slots] (2,097,152 float-slots)

// ---------------------------------------------------------------------------
// 128x128x512 fp32 GEMM (unchanged from R3/R4 — passed).
// ---------------------------------------------------------------------------
template<int EPI>
__global__ __launch_bounds__(256)
void gemm_kernel(const float* __restrict__ A, const float* __restrict__ B,
                 const float* __restrict__ bias, const float* __restrict__ resid,
                 void* P0, void* P1, void* P2, void* P3, void* P4)
{
    const int tid = threadIdx.x;
    const int tm = tid & 15;
    const int tn = tid >> 4;
    const int m0 = blockIdx.y * 128;
    const int n0 = blockIdx.x * 128;
    const int b  = blockIdx.z;

    const float* Bb = B + (size_t)b * XSTRIDE;

    __shared__ float As[16][132];
    __shared__ float Bs[16][132];

    float acc[8][8];
    #pragma unroll
    for (int i = 0; i < 8; ++i)
        #pragma unroll
        for (int j = 0; j < 8; ++j) acc[i][j] = 0.0f;

    for (int k0 = 0; k0 < 512; k0 += 16) {
        {   // A tile [128 m][16 k], A row-major [M][512]
            int id = tid * 2;
            #pragma unroll
            for (int r = 0; r < 2; ++r, ++id) {
                int m = id >> 2, kq = (id & 3) * 4;
                float4 v = *(const float4*)(A + (size_t)(m0 + m) * 512 + k0 + kq);
                As[kq + 0][m] = v.x; As[kq + 1][m] = v.y;
                As[kq + 2][m] = v.z; As[kq + 3][m] = v.w;
            }
        }
        if (EPI != 2) {   // B row-major [512][4096]
            int id = tid * 2;
            #pragma unroll
            for (int r = 0; r < 2; ++r, ++id) {
                int kk = id >> 5, nq = (id & 31) * 4;
                *(float4*)(&Bs[kk][nq]) =
                    *(const float4*)(Bb + (size_t)(k0 + kk) * 4096 + n0 + nq);
            }
        } else {          // B from O halves: c=k0+k -> h=c>>6, d=c&63
            const float* O0p = (const float*)P1;
            const float* O1p = (const float*)P2;
            const int hh = k0 >> 6, d0 = k0 & 63;
            int id = tid * 2;
            #pragma unroll
            for (int r = 0; r < 2; ++r, ++id) {
                int n = id >> 2, kq = (id & 3) * 4;
                int dd = d0 + kq;
                size_t rowp = ((size_t)((b * 8 + hh) * 4096) + n0 + n) * 32;
                const float* src = (dd < 32) ? (O0p + rowp + dd) : (O1p + rowp + dd - 32);
                float4 v = *(const float4*)src;
                Bs[kq + 0][n] = v.x; Bs[kq + 1][n] = v.y;
                Bs[kq + 2][n] = v.z; Bs[kq + 3][n] = v.w;
            }
        }
        __syncthreads();
        #pragma unroll
        for (int k = 0; k < 16; ++k) {
            float4 a0 = *(const float4*)(&As[k][tm * 8]);
            float4 a1 = *(const float4*)(&As[k][tm * 8 + 4]);
            float4 b0 = *(const float4*)(&Bs[k][tn * 8]);
            float4 b1 = *(const float4*)(&Bs[k][tn * 8 + 4]);
            float a[8] = {a0.x, a0.y, a0.z, a0.w, a1.x, a1.y, a1.z, a1.w};
            float bb[8] = {b0.x, b0.y, b0.z, b0.w, b1.x, b1.y, b1.z, b1.w};
            #pragma unroll
            for (int i = 0; i < 8; ++i)
                #pragma unroll
                for (int j = 0; j < 8; ++j)
                    acc[i][j] += a[i] * bb[j];
        }
        __syncthreads();
    }

    if (EPI == 0) {
        const int which = m0 >> 9;              // 0=q 1=k 2=v
        const int mm = (m0 & 511) + tm * 8;
        const int hh = mm >> 6, d0 = mm & 63;
        const size_t rowbase = (size_t)((b * 8 + hh) * 4096);
        if (which == 2) {
            f16* VB = (f16*)P4;
            #pragma unroll
            for (int j = 0; j < 8; ++j) {
                int n = n0 + tn * 8 + j;
                f16x8 v;
                #pragma unroll
                for (int i = 0; i < 8; ++i) v[i] = (f16)acc[i][j];
                *(f16x8*)(VB + (rowbase + n) * 64 + d0) = v;
            }
        } else {
            f16* DH = (f16*)(which ? P2 : P0);
            f16* DL = (f16*)(which ? P3 : P1);
            const float scale = which ? 1.0f : 0.125f;
            #pragma unroll
            for (int j = 0; j < 8; ++j) {
                int n = n0 + tn * 8 + j;
                f16x8 vh, vl;
                #pragma unroll
                for (int i = 0; i < 8; ++i) {
                    float xx = acc[i][j] * scale;
                    f16 hs = (f16)xx;
                    vh[i] = hs;
                    vl[i] = (f16)((xx - (float)hs) * 4096.0f);
                }
                *(f16x8*)(DH + (rowbase + n) * 64 + d0) = vh;
                *(f16x8*)(DL + (rowbase + n) * 64 + d0) = vl;
            }
        }
    } else if (EPI == 1) {
        float* G1 = (float*)P0;
        #pragma unroll
        for (int i = 0; i < 8; ++i) {
            int o = tm * 8 + i;
            float bi = bias[o];
            float* dst = G1 + (size_t)b * G1STRIDE + (size_t)o * 4096 + n0 + tn * 8;
            float v[8];
            #pragma unroll
            for (int j = 0; j < 8; ++j) v[j] = fmaxf(acc[i][j] + bi, 0.0f);
            *(float4*)(dst) = make_float4(v[0], v[1], v[2], v[3]);
            *(float4*)(dst + 4) = make_float4(v[4], v[5], v[6], v[7]);
        }
    } else {
        float* out = (float*)P0;
        #pragma unroll
        for (int i = 0; i < 8; ++i) {
            int o = m0 + tm * 8 + i;
            float bi = bias[o];
            size_t off = (size_t)b * XSTRIDE + (size_t)o * 4096 + n0 + tn * 8;
            float4 r0 = *(const float4*)(resid + off);
            float4 r1 = *(const float4*)(resid + off + 4);
            *(float4*)(out + off) = make_float4(acc[i][0] + bi + r0.x, acc[i][1] + bi + r0.y,
                                                acc[i][2] + bi + r0.z, acc[i][3] + bi + r0.w);
            *(float4*)(out + off + 4) = make_float4(acc[i][4] + bi + r1.x, acc[i][5] + bi + r1.y,
                                                    acc[i][6] + bi + r1.z, acc[i][7] + bi + r1.w);
        }
    }
}

// ---------------------------------------------------------------------------
// gate2 (exact fp32 path — trunc(tau*32) is discrete, do not perturb).
// ---------------------------------------------------------------------------
__global__ __launch_bounds__(64)
void gate2_kernel(const float* __restrict__ G1, const float* __restrict__ w2,
                  const float* __restrict__ b2, int* __restrict__ KD)
{
    const int b = blockIdx.y;
    const int n = blockIdx.x * 64 + threadIdx.x;
    const float* g = G1 + (size_t)b * G1STRIDE + n;
    float z = b2[0];
    #pragma unroll 8
    for (int c = 0; c < 128; ++c) z += w2[c] * g[(size_t)c * 4096];
    float tau = 1.0f / (1.0f + expf(-z));
    int kd = (int)(tau * 32.0f);
    kd = min(32, max(4, kd));
    KD[b * 4096 + n] = kd;
}

// ---------------------------------------------------------------------------
// Kernel A: QK^T (fp16x2 3-pass MFMA) + per-row streaming top-kd over HALF
// the keys. Block = 4 waves / 256 rows / one key-half (2048 keys = 32 tiles).
// R7 fixes: (1) index writeout previously punned the float LDS slab through
// int* (TBAA UB — compiler may hoist int stores above the float value reads,
// corrupting CV); now all LDS stays float-typed via __int_as_float, with a
// __syncthreads() fence between phases. (2) CV relocated to d_out so the ws
// footprint stays at the R1-proven 54.56 MB.
// ---------------------------------------------------------------------------
__global__ __launch_bounds__(256, 2)
void select_kernel(const f16* __restrict__ QH, const f16* __restrict__ QL,
                   const f16* __restrict__ KH, const f16* __restrict__ KL,
                   const int* __restrict__ KD,
                   float* __restrict__ CV, u16* __restrict__ CI)
{
    const int qt = blockIdx.x >> 1;     // row-quad (256 rows)
    const int hf = blockIdx.x & 1;      // key half
    const int h = blockIdx.y, b = blockIdx.z;
    const size_t base = (size_t)((b * 8 + h) * 4096) * 64;
    const int tid = threadIdx.x, lane = tid & 63, w = tid >> 6;
    const int ln = lane & 31, g = lane >> 5;
    const int nw = qt * 256 + w * 64;   // wave's first query row
    const int k0base = hf * 2048;

    __shared__ f16 Ksh[64 * 76];        // stride 76 f16: bank spread on frag reads
    __shared__ f16 Ksl[64 * 76];
    __shared__ float Ss[4][64 * 34];    // per-wave 64 rows x 32 cols (stride 34)

    // Q A-frags resident: A[m=ln][k=16s+8g+j], rb in {0,1}
    f16x8 ah[2][4], al[2][4];
    #pragma unroll
    for (int rb = 0; rb < 2; ++rb) {
        const f16* ph = QH + base + (size_t)(nw + rb * 32 + ln) * 64 + g * 8;
        const f16* pl = QL + base + (size_t)(nw + rb * 32 + ln) * 64 + g * 8;
        #pragma unroll
        for (int s = 0; s < 4; ++s) {
            ah[rb][s] = *(const f16x8*)(ph + s * 16);
            al[rb][s] = *(const f16x8*)(pl + s * 16);
        }
    }

    const float INF = __builtin_inff();
    const int myrow = nw + lane;
    const int kd = KD[b * 4096 + myrow];
    float L[32]; int I[32];
    #pragma unroll
    for (int r = 0; r < 32; ++r) { L[r] = -INF; I[r] = 0; }
    float thr = -INF;                    // tracks L[kd-1]

    // stage tile 0: 512 16B-chunks per buffer; chunk c: row=c>>3, oct=c&7
    {
        const f16* sh = KH + base + (size_t)k0base * 64;
        const f16* sl = KL + base + (size_t)k0base * 64;
        #pragma unroll
        for (int r = 0; r < 2; ++r) {
            int c = tid + r * 256;
            int row = c >> 3, oct = c & 7;
            *(f16x8*)(&Ksh[row * 76 + oct * 8]) = *(const f16x8*)(sh + (size_t)c * 8);
            *(f16x8*)(&Ksl[row * 76 + oct * 8]) = *(const f16x8*)(sl + (size_t)c * 8);
        }
    }
    __syncthreads();

    f16x8 pH0, pH1, pL0, pL1;
    for (int t = 0; t < 32; ++t) {
        if (t < 31) {   // prefetch next tile into regs
            const f16* sh = KH + base + (size_t)(k0base + (t + 1) * 64) * 64;
            const f16* sl = KL + base + (size_t)(k0base + (t + 1) * 64) * 64;
            pH0 = *(const f16x8*)(sh + (size_t)tid * 8);
            pH1 = *(const f16x8*)(sh + (size_t)(tid + 256) * 8);
            pL0 = *(const f16x8*)(sl + (size_t)tid * 8);
            pL1 = *(const f16x8*)(sl + (size_t)(tid + 256) * 8);
        }

        #pragma unroll
        for (int cb = 0; cb < 2; ++cb) {
            // B-frags for this col-half: B[k=16s+8g+j][n=ln] from key row cb*32+ln
            f16x8 bh[4], bl[4];
            #pragma unroll
            for (int s = 0; s < 4; ++s) {
                bh[s] = *(const f16x8*)(&Ksh[(cb * 32 + ln) * 76 + s * 16 + g * 8]);
                bl[s] = *(const f16x8*)(&Ksl[(cb * 32 + ln) * 76 + s * 16 + g * 8]);
            }
            #pragma unroll
            for (int rb = 0; rb < 2; ++rb) {
                f32x16 acc, accL;
                #pragma unroll
                for (int r = 0; r < 16; ++r) { acc[r] = 0.0f; accL[r] = 0.0f; }
                #pragma unroll
                for (int s = 0; s < 4; ++s) {
                    acc  = __builtin_amdgcn_mfma_f32_32x32x16_f16(ah[rb][s], bh[s], acc,  0, 0, 0);
                    accL = __builtin_amdgcn_mfma_f32_32x32x16_f16(al[rb][s], bh[s], accL, 0, 0, 0);
                    accL = __builtin_amdgcn_mfma_f32_32x32x16_f16(ah[rb][s], bl[s], accL, 0, 0, 0);
                }
                // C layout: row=(r&3)+8*(r>>2)+4g, col=ln (verified m74/m101)
                #pragma unroll
                for (int r = 0; r < 16; ++r) {
                    int riw = rb * 32 + (r & 3) + 8 * (r >> 2) + 4 * g;
                    Ss[w][riw * 34 + ln] = acc[r] + accL[r] * (1.0f / 4096.0f);
                }
            }
            // same-wave LDS is in-order: scan sees the writes, no barrier.

            // ---- scan own row -> capture bitmask (branch-free) ----
            u32 m = 0;
            {
                const float* srow = &Ss[w][lane * 34];
                #pragma unroll
                for (int q = 0; q < 16; ++q) {
                    float2 v = *(const float2*)(srow + 2 * q);
                    m |= (v.x > thr) ? (1u << (2 * q)) : 0u;
                    m |= (v.y > thr) ? (1u << (2 * q + 1)) : 0u;
                }
            }
            // ---- drain: iterations = wave-max popcount ----
            while (__ballot(m != 0u)) {
                bool act = (m != 0u);
                int j = __builtin_ctz(m ? m : 1u);      // lowest set bit (valid iff act)
                float c = act ? Ss[w][lane * 34 + j] : 0.0f;
                m &= (m - 1u);
                if (act && c > thr) {
                    int jj = k0base + t * 64 + cb * 32 + j;
                    #pragma unroll
                    for (int r = 31; r >= 1; --r) {
                        bool gp = c > L[r - 1];
                        bool gc = c > L[r];
                        float nL = gp ? L[r - 1] : (gc ? c : L[r]);
                        int   nI = gp ? I[r - 1] : (gc ? jj : I[r]);
                        L[r] = nL; I[r] = nI;
                        if (r == kd - 1) thr = nL;      // kd-1 in [3,31]
                    }
                    if (c > L[0]) { I[0] = jj; L[0] = c; }
                }
            }
        }

        __syncthreads();                 // all waves done with Ks tile t
        if (t < 31) {
            #pragma unroll
            for (int r = 0; r < 2; ++r) {
                int c = tid + r * 256;
                int row = c >> 3, oct = c & 7;
                *(f16x8*)(&Ksh[row * 76 + oct * 8]) = (r == 0) ? pH0 : pH1;
                *(f16x8*)(&Ksl[row * 76 + oct * 8]) = (r == 0) ? pL0 : pL1;
            }
        }
        __syncthreads();                 // Ks tile t+1 ready
    }

    // ---- writeout (all LDS traffic float-typed; fence between phases) ----
    const size_t crow0 = (size_t)((b * 8 + h) * 4096 + nw);
    // phase 1: values
    #pragma unroll
    for (int r = 0; r < 32; ++r) Ss[w][lane * 34 + r] = L[r];
    for (int i = 0; i < 32; ++i) {
        int f = i * 64 + lane;           // 64 rows x 32 slots, bijective
        int row = f >> 5, sl = f & 31;
        CV[(crow0 + row) * 64 + hf * 32 + sl] = Ss[w][row * 34 + sl];
    }
    __syncthreads();                     // value reads complete before overwrite
    // phase 2: indices as float bit-patterns (no int*/float* punning)
    #pragma unroll
    for (int r = 0; r < 32; ++r) Ss[w][lane * 34 + r] = __int_as_float(I[r]);
    for (int i = 0; i < 32; ++i) {
        int f = i * 64 + lane;
        int row = f >> 5, sl = f & 31;
        CI[(crow0 + row) * 64 + hf * 32 + sl] =
            (u16)__float_as_uint(Ss[w][row * 34 + sl]);
    }
}

// ---------------------------------------------------------------------------
// Kernel B: merge the two sorted half-lists per row (tie -> half 0 = earlier
// index, exact jax top_k semantics), softmax in rank order, gather V, write O.
// Block = 64 threads = 64 rows (one per thread); grid 1024.
// ---------------------------------------------------------------------------
__global__ __launch_bounds__(64)
void merge_kernel(const float* __restrict__ CV, const u16* __restrict__ CI,
                  const int* __restrict__ KD, const f16* __restrict__ VB,
                  float* __restrict__ O0, float* __restrict__ O1)
{
    const int tid = threadIdx.x;
    const size_t R0 = (size_t)blockIdx.x * 64;

    __shared__ float Lv[64][66];
    __shared__ u16   Li[64][66];
    __shared__ float Mv[64][34];
    __shared__ u16   Mi[64][34];

    for (int i = 0; i < 64; ++i) {       // coalesced stage
        Lv[i][tid] = CV[(R0 + i) * 64 + tid];
        Li[i][tid] = CI[(R0 + i) * 64 + tid];
    }
    __syncthreads();

    const int myR = (int)R0 + tid;       // = (b*8+h)*4096 + n
    const int b = myR >> 15, n = myR & 4095, h = (myR >> 12) & 7;
    const int kd = KD[b * 4096 + n];

    // merge two desc-sorted lists; reads bounded at p<=kd-1<=31 per half
    int p0 = 0, p1 = 0;
    const float mx = fmaxf(Lv[tid][0], Lv[tid][32]);
    float sum = 0.0f;
    for (int k = 0; k < kd; ++k) {
        float v0 = Lv[tid][p0];
        float v1 = Lv[tid][32 + p1];
        bool take0 = (v0 >= v1);         // tie -> half 0 (earlier index)
        float v  = take0 ? v0 : v1;
        u16   ix = take0 ? Li[tid][p0] : Li[tid][32 + p1];
        p0 += take0 ? 1 : 0; p1 += take0 ? 0 : 1;
        float e = expf(v - mx);          // rank order, matches reference
        Mv[tid][k] = e; Mi[tid][k] = ix;
        sum += e;
    }
    const float inv = 1.0f / sum;

    float o[64];
    #pragma unroll
    for (int d = 0; d < 64; ++d) o[d] = 0.0f;
    const size_t vbase = (size_t)((b * 8 + h)) * 4096 * 64;
    for (int k = 0; k < kd; ++k) {
        float wgt = Mv[tid][k] * inv;
        const f16* vp = VB + vbase + (size_t)Mi[tid][k] * 64;
        #pragma unroll
        for (int part = 0; part < 8; ++part) {
            f16x8 vv = *(const f16x8*)(vp + part * 8);
            #pragma unroll
            for (int e2 = 0; e2 < 8; ++e2) o[part * 8 + e2] += wgt * (float)vv[e2];
        }
    }

    __syncthreads();                     // done reading Lv lists
    #pragma unroll
    for (int q = 0; q < 32; ++q)
        *(float2*)(&Lv[tid][2 * q]) = make_float2(o[2 * q], o[2 * q + 1]);
    __syncthreads();
    for (int i = 0; i < 64; ++i) {       // coalesced O store
        float val = Lv[i][tid];
        size_t R = R0 + i;
        if (tid < 32) O0[R * 32 + tid] = val;
        else          O1[R * 32 + (tid - 32)] = val;
    }
}

// ---------------------------------------------------------------------------
extern "C" void kernel_launch(void* const* d_in, const int* in_sizes, int n_in,
                              void* d_out, int out_size, void* d_ws, size_t ws_size,
                              hipStream_t stream)
{
    const float* x      = (const float*)d_in[0];
    const float* w_qkv  = (const float*)d_in[1];
    const float* w_proj = (const float*)d_in[2];
    const float* b_proj = (const float*)d_in[3];
    const float* w_g1   = (const float*)d_in[4];
    const float* b_g1   = (const float*)d_in[5];
    const float* w_g2   = (const float*)d_in[6];
    const float* b_g2   = (const float*)d_in[7];
    float* out = (float*)d_out;
    float* ws  = (float*)d_ws;

    f16* QH = (f16*)(ws + WS_QH);
    f16* QL = (f16*)(ws + WS_QL);
    f16* KH = (f16*)(ws + WS_KH);
    f16* KL = (f16*)(ws + WS_KL);
    f16* VB = (f16*)(ws + WS_VB);
    float* G1 = ws + WS_G1;
    int*   KD = (int*)(ws + WS_KD);
    u16*   CI = (u16*)(ws + WS_CI);
    float* CV = out;          // d_out as CV scratch (select->merge, then proj overwrites)
    float* O0 = (float*)QH;   // overlay: O replaces Q hi/lo (select done before merge)
    float* O1 = (float*)QL;

    gemm_kernel<0><<<dim3(32, 12, 2), 256, 0, stream>>>(
        w_qkv, x, nullptr, nullptr, QH, QL, KH, KL, VB);
    gemm_kernel<1><<<dim3(32, 1, 2), 256, 0, stream>>>(
        w_g1, x, b_g1, nullptr, G1, nullptr, nullptr, nullptr, nullptr);
    gate2_kernel<<<dim3(64, 2), 64, 0, stream>>>(G1, w_g2, b_g2, KD);
    select_kernel<<<dim3(32, 8, 2), 256, 0, stream>>>(QH, QL, KH, KL, KD, CV, CI);
    merge_kernel<<<dim3(1024), 64, 0, stream>>>(CV, CI, KD, VB, O0, O1);
    gemm_kernel<2><<<dim3(32, 4, 2), 256, 0, stream>>>(
        w_proj, nullptr, b_proj, x, out, O0, O1, nullptr, nullptr);
}

// Round 8
// 1076.836 us; speedup vs baseline: 1.9026x; 1.0393x over previous
//
#include <hip/hip_runtime.h>
#include <math.h>

// Problem constants: B=2, C=512, H=8 heads, dh=64, N=4096, Kmax=32
#define XSTRIDE  2097152u  // 512*4096 per-batch stride of x / out
#define G1STRIDE 524288u   // 128*4096

typedef _Float16 f16;
typedef f16   f16x8  __attribute__((ext_vector_type(8)));
typedef float f32x16 __attribute__((ext_vector_type(16)));
typedef unsigned int u32;
typedef unsigned short u16;

// ws layout (float offsets). Total 13,639,680 floats = 54.56 MB (R1-proven).
// CV lives in d_out (4,194,304 floats): select writes, merge reads, proj
// overwrites d_out afterward.
#define WS_QH 0u          // f16 [2][8][4096][64]
#define WS_QL 2097152u    // f16 lo parts, pre-scaled x4096
#define WS_KH 4194304u
#define WS_KL 6291456u
#define WS_VB 8388608u    // f16 V
#define WS_G1 10485760u   // f32 [2][128][4096]
#define WS_KD 11534336u   // int [2][4096]
#define WS_CI 11542528u   // u16 [65536 rows][64 slots] (2,097,152 float-slots)

// ---------------------------------------------------------------------------
// 128x128x512 fp32 GEMM (unchanged from R3..R7 — passed).
// ---------------------------------------------------------------------------
template<int EPI>
__global__ __launch_bounds__(256)
void gemm_kernel(const float* __restrict__ A, const float* __restrict__ B,
                 const float* __restrict__ bias, const float* __restrict__ resid,
                 void* P0, void* P1, void* P2, void* P3, void* P4)
{
    const int tid = threadIdx.x;
    const int tm = tid & 15;
    const int tn = tid >> 4;
    const int m0 = blockIdx.y * 128;
    const int n0 = blockIdx.x * 128;
    const int b  = blockIdx.z;

    const float* Bb = B + (size_t)b * XSTRIDE;

    __shared__ float As[16][132];
    __shared__ float Bs[16][132];

    float acc[8][8];
    #pragma unroll
    for (int i = 0; i < 8; ++i)
        #pragma unroll
        for (int j = 0; j < 8; ++j) acc[i][j] = 0.0f;

    for (int k0 = 0; k0 < 512; k0 += 16) {
        {   // A tile [128 m][16 k], A row-major [M][512]
            int id = tid * 2;
            #pragma unroll
            for (int r = 0; r < 2; ++r, ++id) {
                int m = id >> 2, kq = (id & 3) * 4;
                float4 v = *(const float4*)(A + (size_t)(m0 + m) * 512 + k0 + kq);
                As[kq + 0][m] = v.x; As[kq + 1][m] = v.y;
                As[kq + 2][m] = v.z; As[kq + 3][m] = v.w;
            }
        }
        if (EPI != 2) {   // B row-major [512][4096]
            int id = tid * 2;
            #pragma unroll
            for (int r = 0; r < 2; ++r, ++id) {
                int kk = id >> 5, nq = (id & 31) * 4;
                *(float4*)(&Bs[kk][nq]) =
                    *(const float4*)(Bb + (size_t)(k0 + kk) * 4096 + n0 + nq);
            }
        } else {          // B from O halves: c=k0+k -> h=c>>6, d=c&63
            const float* O0p = (const float*)P1;
            const float* O1p = (const float*)P2;
            const int hh = k0 >> 6, d0 = k0 & 63;
            int id = tid * 2;
            #pragma unroll
            for (int r = 0; r < 2; ++r, ++id) {
                int n = id >> 2, kq = (id & 3) * 4;
                int dd = d0 + kq;
                size_t rowp = ((size_t)((b * 8 + hh) * 4096) + n0 + n) * 32;
                const float* src = (dd < 32) ? (O0p + rowp + dd) : (O1p + rowp + dd - 32);
                float4 v = *(const float4*)src;
                Bs[kq + 0][n] = v.x; Bs[kq + 1][n] = v.y;
                Bs[kq + 2][n] = v.z; Bs[kq + 3][n] = v.w;
            }
        }
        __syncthreads();
        #pragma unroll
        for (int k = 0; k < 16; ++k) {
            float4 a0 = *(const float4*)(&As[k][tm * 8]);
            float4 a1 = *(const float4*)(&As[k][tm * 8 + 4]);
            float4 b0 = *(const float4*)(&Bs[k][tn * 8]);
            float4 b1 = *(const float4*)(&Bs[k][tn * 8 + 4]);
            float a[8] = {a0.x, a0.y, a0.z, a0.w, a1.x, a1.y, a1.z, a1.w};
            float bb[8] = {b0.x, b0.y, b0.z, b0.w, b1.x, b1.y, b1.z, b1.w};
            #pragma unroll
            for (int i = 0; i < 8; ++i)
                #pragma unroll
                for (int j = 0; j < 8; ++j)
                    acc[i][j] += a[i] * bb[j];
        }
        __syncthreads();
    }

    if (EPI == 0) {
        const int which = m0 >> 9;              // 0=q 1=k 2=v
        const int mm = (m0 & 511) + tm * 8;
        const int hh = mm >> 6, d0 = mm & 63;
        const size_t rowbase = (size_t)((b * 8 + hh) * 4096);
        if (which == 2) {
            f16* VB = (f16*)P4;
            #pragma unroll
            for (int j = 0; j < 8; ++j) {
                int n = n0 + tn * 8 + j;
                f16x8 v;
                #pragma unroll
                for (int i = 0; i < 8; ++i) v[i] = (f16)acc[i][j];
                *(f16x8*)(VB + (rowbase + n) * 64 + d0) = v;
            }
        } else {
            f16* DH = (f16*)(which ? P2 : P0);
            f16* DL = (f16*)(which ? P3 : P1);
            const float scale = which ? 1.0f : 0.125f;
            #pragma unroll
            for (int j = 0; j < 8; ++j) {
                int n = n0 + tn * 8 + j;
                f16x8 vh, vl;
                #pragma unroll
                for (int i = 0; i < 8; ++i) {
                    float xx = acc[i][j] * scale;
                    f16 hs = (f16)xx;
                    vh[i] = hs;
                    vl[i] = (f16)((xx - (float)hs) * 4096.0f);
                }
                *(f16x8*)(DH + (rowbase + n) * 64 + d0) = vh;
                *(f16x8*)(DL + (rowbase + n) * 64 + d0) = vl;
            }
        }
    } else if (EPI == 1) {
        float* G1 = (float*)P0;
        #pragma unroll
        for (int i = 0; i < 8; ++i) {
            int o = tm * 8 + i;
            float bi = bias[o];
            float* dst = G1 + (size_t)b * G1STRIDE + (size_t)o * 4096 + n0 + tn * 8;
            float v[8];
            #pragma unroll
            for (int j = 0; j < 8; ++j) v[j] = fmaxf(acc[i][j] + bi, 0.0f);
            *(float4*)(dst) = make_float4(v[0], v[1], v[2], v[3]);
            *(float4*)(dst + 4) = make_float4(v[4], v[5], v[6], v[7]);
        }
    } else {
        float* out = (float*)P0;
        #pragma unroll
        for (int i = 0; i < 8; ++i) {
            int o = m0 + tm * 8 + i;
            float bi = bias[o];
            size_t off = (size_t)b * XSTRIDE + (size_t)o * 4096 + n0 + tn * 8;
            float4 r0 = *(const float4*)(resid + off);
            float4 r1 = *(const float4*)(resid + off + 4);
            *(float4*)(out + off) = make_float4(acc[i][0] + bi + r0.x, acc[i][1] + bi + r0.y,
                                                acc[i][2] + bi + r0.z, acc[i][3] + bi + r0.w);
            *(float4*)(out + off + 4) = make_float4(acc[i][4] + bi + r1.x, acc[i][5] + bi + r1.y,
                                                    acc[i][6] + bi + r1.z, acc[i][7] + bi + r1.w);
        }
    }
}

// ---------------------------------------------------------------------------
// gate2 (exact fp32 path — trunc(tau*32) is discrete, do not perturb).
// ---------------------------------------------------------------------------
__global__ __launch_bounds__(64)
void gate2_kernel(const float* __restrict__ G1, const float* __restrict__ w2,
                  const float* __restrict__ b2, int* __restrict__ KD)
{
    const int b = blockIdx.y;
    const int n = blockIdx.x * 64 + threadIdx.x;
    const float* g = G1 + (size_t)b * G1STRIDE + n;
    float z = b2[0];
    #pragma unroll 8
    for (int c = 0; c < 128; ++c) z += w2[c] * g[(size_t)c * 4096];
    float tau = 1.0f / (1.0f + expf(-z));
    int kd = (int)(tau * 32.0f);
    kd = min(32, max(4, kd));
    KD[b * 4096 + n] = kd;
}

// ---------------------------------------------------------------------------
// select v2 (R8): one wave per block, NO barriers, NO K LDS (B-frags loaded
// directly from global — L2-hot), LDS = 8.7 KB score slab only. Class-split
// by wave-max kd: DEPTH=16 kernel handles waves with mk<=16 (half-size L/I,
// half-cost insert), DEPTH=32 the rest; both launched full-grid, early exit.
// launch_bounds(64,2) => <=256 VGPRs => no scratch spill (R7's 778 µs +
// 10x WRITE_SIZE diagnosed as L/I spill at VGPR=128).
// Score math bit-identical to R3..R7 (fp16x2 3-pass MFMA).
// ---------------------------------------------------------------------------
template<int DEPTH>
__global__ __launch_bounds__(64, 2)
void select_kernel(const f16* __restrict__ QH, const f16* __restrict__ QL,
                   const f16* __restrict__ KH, const f16* __restrict__ KL,
                   const int* __restrict__ KD,
                   float* __restrict__ CV, u16* __restrict__ CI)
{
    const int qt = blockIdx.x >> 1;     // 64-row group
    const int hf = blockIdx.x & 1;      // key half
    const int h = blockIdx.y, b = blockIdx.z;
    const size_t base = (size_t)((b * 8 + h) * 4096) * 64;
    const int lane = threadIdx.x;       // 0..63
    const int ln = lane & 31, g = lane >> 5;
    const int nw = qt * 64;
    const int k0base = hf * 2048;

    const int kd = KD[b * 4096 + nw + lane];
    int mk = kd;
    #pragma unroll
    for (int sh = 1; sh < 64; sh <<= 1) mk = max(mk, __shfl_xor(mk, sh));
    if (DEPTH == 16) { if (mk > 16) return; }
    else             { if (mk <= 16) return; }

    __shared__ float Ss[64 * 34];       // own wave's 64 rows x 32 cols (stride 34: b64-aligned)

    // resident Q frags: A[m=ln][k=16s+8g+j]
    f16x8 ah[2][4], al[2][4];
    #pragma unroll
    for (int rb = 0; rb < 2; ++rb) {
        const f16* ph = QH + base + (size_t)(nw + rb * 32 + ln) * 64 + g * 8;
        const f16* pl = QL + base + (size_t)(nw + rb * 32 + ln) * 64 + g * 8;
        #pragma unroll
        for (int s = 0; s < 4; ++s) {
            ah[rb][s] = *(const f16x8*)(ph + s * 16);
            al[rb][s] = *(const f16x8*)(pl + s * 16);
        }
    }

    const float INF = __builtin_inff();
    float L[DEPTH]; int I[DEPTH];
    #pragma unroll
    for (int r = 0; r < DEPTH; ++r) { L[r] = -INF; I[r] = 0; }
    float thr = -INF;                    // tracks L[kd-1]

    for (int t = 0; t < 32; ++t) {
        const f16* kh_t = KH + base + (size_t)(k0base + t * 64) * 64;
        const f16* kl_t = KL + base + (size_t)(k0base + t * 64) * 64;
        #pragma unroll
        for (int cb = 0; cb < 2; ++cb) {
            #pragma unroll
            for (int rb = 0; rb < 2; ++rb) {
                f32x16 acc, accL;
                #pragma unroll
                for (int r = 0; r < 16; ++r) { acc[r] = 0.0f; accL[r] = 0.0f; }
                #pragma unroll
                for (int s = 0; s < 4; ++s) {
                    // B-frag: B[k=16s+8g+j][n=ln] = K[key=cb*32+ln][d] straight from global
                    f16x8 bh = *(const f16x8*)(kh_t + (size_t)(cb * 32 + ln) * 64 + s * 16 + g * 8);
                    f16x8 bl = *(const f16x8*)(kl_t + (size_t)(cb * 32 + ln) * 64 + s * 16 + g * 8);
                    acc  = __builtin_amdgcn_mfma_f32_32x32x16_f16(ah[rb][s], bh, acc,  0, 0, 0);
                    accL = __builtin_amdgcn_mfma_f32_32x32x16_f16(al[rb][s], bh, accL, 0, 0, 0);
                    accL = __builtin_amdgcn_mfma_f32_32x32x16_f16(ah[rb][s], bl, accL, 0, 0, 0);
                }
                // C layout: row=(r&3)+8*(r>>2)+4g, col=ln (verified m74/m101)
                #pragma unroll
                for (int r = 0; r < 16; ++r) {
                    int riw = rb * 32 + (r & 3) + 8 * (r >> 2) + 4 * g;
                    Ss[riw * 34 + ln] = acc[r] + accL[r] * (1.0f / 4096.0f);
                }
            }
            // same-wave LDS is in-order: scan below sees the park writes.

            // ---- scan own row -> candidate bitmask (branch-free) ----
            u32 m = 0;
            const float* srow = &Ss[lane * 34];
            #pragma unroll
            for (int q = 0; q < 16; ++q) {
                float2 v = *(const float2*)(srow + 2 * q);
                m |= (v.x > thr) ? (1u << (2 * q)) : 0u;
                m |= (v.y > thr) ? (1u << (2 * q + 1)) : 0u;
            }
            // ---- drain: iterations = wave-max popcount ----
            const int jbase = k0base + t * 64 + cb * 32;
            while (__ballot(m != 0u)) {
                bool act = (m != 0u);
                int j = __builtin_ctz(m ? m : 1u);      // lowest set bit (valid iff act)
                float c = act ? srow[j] : 0.0f;
                m &= (m - 1u);
                if (act && c > thr) {
                    int jj = jbase + j;
                    #pragma unroll
                    for (int r = DEPTH - 1; r >= 1; --r) {
                        bool gp = c > L[r - 1];
                        bool gc = c > L[r];
                        float nL = gp ? L[r - 1] : (gc ? c : L[r]);
                        int   nI = gp ? I[r - 1] : (gc ? jj : I[r]);
                        L[r] = nL; I[r] = nI;
                        if (r == kd - 1) thr = nL;      // kd-1 in [3,DEPTH-1]
                    }
                    if (c > L[0]) { I[0] = jj; L[0] = c; }
                }
            }
        }
    }

    // ---- writeout via transpose slab (same-wave, in-order) ----
    const size_t crow0 = (size_t)((b * 8 + h) * 4096 + nw);
    #pragma unroll
    for (int r = 0; r < 32; ++r)
        Ss[lane * 34 + r] = (r < DEPTH) ? L[r] : -INF;
    #pragma unroll
    for (int i = 0; i < 32; ++i) {
        int f = i * 64 + lane;           // 64 rows x 32 slots, bijective
        int row = f >> 5, sl = f & 31;
        CV[(crow0 + row) * 64 + hf * 32 + sl] = Ss[row * 34 + sl];
    }
    #pragma unroll
    for (int r = 0; r < 32; ++r)
        Ss[lane * 34 + r] = __int_as_float((r < DEPTH) ? I[r] : 0);
    #pragma unroll
    for (int i = 0; i < 32; ++i) {
        int f = i * 64 + lane;
        int row = f >> 5, sl = f & 31;
        CI[(crow0 + row) * 64 + hf * 32 + sl] =
            (u16)__float_as_uint(Ss[row * 34 + sl]);
    }
}

// ---------------------------------------------------------------------------
// Kernel B: merge the two sorted half-lists per row (tie -> half 0 = earlier
// index, exact jax top_k semantics), softmax in rank order, gather V, write O.
// ---------------------------------------------------------------------------
__global__ __launch_bounds__(64)
void merge_kernel(const float* __restrict__ CV, const u16* __restrict__ CI,
                  const int* __restrict__ KD, const f16* __restrict__ VB,
                  float* __restrict__ O0, float* __restrict__ O1)
{
    const int tid = threadIdx.x;
    const size_t R0 = (size_t)blockIdx.x * 64;

    __shared__ float Lv[64][66];
    __shared__ u16   Li[64][66];
    __shared__ float Mv[64][34];
    __shared__ u16   Mi[64][34];

    for (int i = 0; i < 64; ++i) {       // coalesced stage
        Lv[i][tid] = CV[(R0 + i) * 64 + tid];
        Li[i][tid] = CI[(R0 + i) * 64 + tid];
    }
    __syncthreads();

    const int myR = (int)R0 + tid;       // = (b*8+h)*4096 + n
    const int b = myR >> 15, n = myR & 4095, h = (myR >> 12) & 7;
    const int kd = KD[b * 4096 + n];

    // merge two desc-sorted lists; reads bounded at p<=kd-1<=31 per half
    int p0 = 0, p1 = 0;
    const float mx = fmaxf(Lv[tid][0], Lv[tid][32]);
    float sum = 0.0f;
    for (int k = 0; k < kd; ++k) {
        float v0 = Lv[tid][p0];
        float v1 = Lv[tid][32 + p1];
        bool take0 = (v0 >= v1);         // tie -> half 0 (earlier index)
        float v  = take0 ? v0 : v1;
        u16   ix = take0 ? Li[tid][p0] : Li[tid][32 + p1];
        p0 += take0 ? 1 : 0; p1 += take0 ? 0 : 1;
        float e = expf(v - mx);          // rank order, matches reference
        Mv[tid][k] = e; Mi[tid][k] = ix;
        sum += e;
    }
    const float inv = 1.0f / sum;

    float o[64];
    #pragma unroll
    for (int d = 0; d < 64; ++d) o[d] = 0.0f;
    const size_t vbase = (size_t)((b * 8 + h)) * 4096 * 64;
    for (int k = 0; k < kd; ++k) {
        float wgt = Mv[tid][k] * inv;
        const f16* vp = VB + vbase + (size_t)Mi[tid][k] * 64;
        #pragma unroll
        for (int part = 0; part < 8; ++part) {
            f16x8 vv = *(const f16x8*)(vp + part * 8);
            #pragma unroll
            for (int e2 = 0; e2 < 8; ++e2) o[part * 8 + e2] += wgt * (float)vv[e2];
        }
    }

    __syncthreads();                     // done reading Lv lists
    #pragma unroll
    for (int q = 0; q < 32; ++q)
        *(float2*)(&Lv[tid][2 * q]) = make_float2(o[2 * q], o[2 * q + 1]);
    __syncthreads();
    for (int i = 0; i < 64; ++i) {       // coalesced O store
        float val = Lv[i][tid];
        size_t R = R0 + i;
        if (tid < 32) O0[R * 32 + tid] = val;
        else          O1[R * 32 + (tid - 32)] = val;
    }
}

// ---------------------------------------------------------------------------
extern "C" void kernel_launch(void* const* d_in, const int* in_sizes, int n_in,
                              void* d_out, int out_size, void* d_ws, size_t ws_size,
                              hipStream_t stream)
{
    const float* x      = (const float*)d_in[0];
    const float* w_qkv  = (const float*)d_in[1];
    const float* w_proj = (const float*)d_in[2];
    const float* b_proj = (const float*)d_in[3];
    const float* w_g1   = (const float*)d_in[4];
    const float* b_g1   = (const float*)d_in[5];
    const float* w_g2   = (const float*)d_in[6];
    const float* b_g2   = (const float*)d_in[7];
    float* out = (float*)d_out;
    float* ws  = (float*)d_ws;

    f16* QH = (f16*)(ws + WS_QH);
    f16* QL = (f16*)(ws + WS_QL);
    f16* KH = (f16*)(ws + WS_KH);
    f16* KL = (f16*)(ws + WS_KL);
    f16* VB = (f16*)(ws + WS_VB);
    float* G1 = ws + WS_G1;
    int*   KD = (int*)(ws + WS_KD);
    u16*   CI = (u16*)(ws + WS_CI);
    float* CV = out;          // d_out as CV scratch (select->merge, then proj overwrites)
    float* O0 = (float*)QH;   // overlay: O replaces Q hi/lo (select done before merge)
    float* O1 = (float*)QL;

    gemm_kernel<0><<<dim3(32, 12, 2), 256, 0, stream>>>(
        w_qkv, x, nullptr, nullptr, QH, QL, KH, KL, VB);
    gemm_kernel<1><<<dim3(32, 1, 2), 256, 0, stream>>>(
        w_g1, x, b_g1, nullptr, G1, nullptr, nullptr, nullptr, nullptr);
    gate2_kernel<<<dim3(64, 2), 64, 0, stream>>>(G1, w_g2, b_g2, KD);
    select_kernel<16><<<dim3(128, 8, 2), 64, 0, stream>>>(QH, QL, KH, KL, KD, CV, CI);
    select_kernel<32><<<dim3(128, 8, 2), 64, 0, stream>>>(QH, QL, KH, KL, KD, CV, CI);
    merge_kernel<<<dim3(1024), 64, 0, stream>>>(CV, CI, KD, VB, O0, O1);
    gemm_kernel<2><<<dim3(32, 4, 2), 256, 0, stream>>>(
        w_proj, nullptr, b_proj, x, out, O0, O1, nullptr, nullptr);
}

// Round 9
// 833.276 us; speedup vs baseline: 2.4588x; 1.2923x over previous
//
#include <hip/hip_runtime.h>
#include <math.h>

// Problem constants: B=2, C=512, H=8 heads, dh=64, N=4096, Kmax=32
#define XSTRIDE  2097152u  // 512*4096 per-batch stride of x / out
#define G1STRIDE 524288u   // 128*4096

typedef _Float16 f16;
typedef f16   f16x8  __attribute__((ext_vector_type(8)));
typedef float f32x16 __attribute__((ext_vector_type(16)));
typedef unsigned int u32;
typedef unsigned short u16;

// ws layout (float offsets). Total 13,639,680 floats = 54.56 MB (R1-proven).
// CV lives in d_out (4,194,304 floats): memset NaN -> select appends -> merge
// reads -> proj overwrites d_out.
#define WS_QH 0u          // f16 [2][8][4096][64]
#define WS_QL 2097152u    // f16 lo parts, pre-scaled x4096
#define WS_KH 4194304u
#define WS_KL 6291456u
#define WS_VB 8388608u    // f16 V
#define WS_G1 10485760u   // f32 [2][128][4096]
#define WS_KD 11534336u   // int [2][4096]
#define WS_CI 11542528u   // u16 [65536 rows][64 slots] (2,097,152 float-slots)

// ---------------------------------------------------------------------------
// 128x128x512 fp32 GEMM (unchanged from R3..R8 — passed).
// ---------------------------------------------------------------------------
template<int EPI>
__global__ __launch_bounds__(256)
void gemm_kernel(const float* __restrict__ A, const float* __restrict__ B,
                 const float* __restrict__ bias, const float* __restrict__ resid,
                 void* P0, void* P1, void* P2, void* P3, void* P4)
{
    const int tid = threadIdx.x;
    const int tm = tid & 15;
    const int tn = tid >> 4;
    const int m0 = blockIdx.y * 128;
    const int n0 = blockIdx.x * 128;
    const int b  = blockIdx.z;

    const float* Bb = B + (size_t)b * XSTRIDE;

    __shared__ float As[16][132];
    __shared__ float Bs[16][132];

    float acc[8][8];
    #pragma unroll
    for (int i = 0; i < 8; ++i)
        #pragma unroll
        for (int j = 0; j < 8; ++j) acc[i][j] = 0.0f;

    for (int k0 = 0; k0 < 512; k0 += 16) {
        {   // A tile [128 m][16 k], A row-major [M][512]
            int id = tid * 2;
            #pragma unroll
            for (int r = 0; r < 2; ++r, ++id) {
                int m = id >> 2, kq = (id & 3) * 4;
                float4 v = *(const float4*)(A + (size_t)(m0 + m) * 512 + k0 + kq);
                As[kq + 0][m] = v.x; As[kq + 1][m] = v.y;
                As[kq + 2][m] = v.z; As[kq + 3][m] = v.w;
            }
        }
        if (EPI != 2) {   // B row-major [512][4096]
            int id = tid * 2;
            #pragma unroll
            for (int r = 0; r < 2; ++r, ++id) {
                int kk = id >> 5, nq = (id & 31) * 4;
                *(float4*)(&Bs[kk][nq]) =
                    *(const float4*)(Bb + (size_t)(k0 + kk) * 4096 + n0 + nq);
            }
        } else {          // B from O halves: c=k0+k -> h=c>>6, d=c&63
            const float* O0p = (const float*)P1;
            const float* O1p = (const float*)P2;
            const int hh = k0 >> 6, d0 = k0 & 63;
            int id = tid * 2;
            #pragma unroll
            for (int r = 0; r < 2; ++r, ++id) {
                int n = id >> 2, kq = (id & 3) * 4;
                int dd = d0 + kq;
                size_t rowp = ((size_t)((b * 8 + hh) * 4096) + n0 + n) * 32;
                const float* src = (dd < 32) ? (O0p + rowp + dd) : (O1p + rowp + dd - 32);
                float4 v = *(const float4*)src;
                Bs[kq + 0][n] = v.x; Bs[kq + 1][n] = v.y;
                Bs[kq + 2][n] = v.z; Bs[kq + 3][n] = v.w;
            }
        }
        __syncthreads();
        #pragma unroll
        for (int k = 0; k < 16; ++k) {
            float4 a0 = *(const float4*)(&As[k][tm * 8]);
            float4 a1 = *(const float4*)(&As[k][tm * 8 + 4]);
            float4 b0 = *(const float4*)(&Bs[k][tn * 8]);
            float4 b1 = *(const float4*)(&Bs[k][tn * 8 + 4]);
            float a[8] = {a0.x, a0.y, a0.z, a0.w, a1.x, a1.y, a1.z, a1.w};
            float bb[8] = {b0.x, b0.y, b0.z, b0.w, b1.x, b1.y, b1.z, b1.w};
            #pragma unroll
            for (int i = 0; i < 8; ++i)
                #pragma unroll
                for (int j = 0; j < 8; ++j)
                    acc[i][j] += a[i] * bb[j];
        }
        __syncthreads();
    }

    if (EPI == 0) {
        const int which = m0 >> 9;              // 0=q 1=k 2=v
        const int mm = (m0 & 511) + tm * 8;
        const int hh = mm >> 6, d0 = mm & 63;
        const size_t rowbase = (size_t)((b * 8 + hh) * 4096);
        if (which == 2) {
            f16* VB = (f16*)P4;
            #pragma unroll
            for (int j = 0; j < 8; ++j) {
                int n = n0 + tn * 8 + j;
                f16x8 v;
                #pragma unroll
                for (int i = 0; i < 8; ++i) v[i] = (f16)acc[i][j];
                *(f16x8*)(VB + (rowbase + n) * 64 + d0) = v;
            }
        } else {
            f16* DH = (f16*)(which ? P2 : P0);
            f16* DL = (f16*)(which ? P3 : P1);
            const float scale = which ? 1.0f : 0.125f;
            #pragma unroll
            for (int j = 0; j < 8; ++j) {
                int n = n0 + tn * 8 + j;
                f16x8 vh, vl;
                #pragma unroll
                for (int i = 0; i < 8; ++i) {
                    float xx = acc[i][j] * scale;
                    f16 hs = (f16)xx;
                    vh[i] = hs;
                    vl[i] = (f16)((xx - (float)hs) * 4096.0f);
                }
                *(f16x8*)(DH + (rowbase + n) * 64 + d0) = vh;
                *(f16x8*)(DL + (rowbase + n) * 64 + d0) = vl;
            }
        }
    } else if (EPI == 1) {
        float* G1 = (float*)P0;
        #pragma unroll
        for (int i = 0; i < 8; ++i) {
            int o = tm * 8 + i;
            float bi = bias[o];
            float* dst = G1 + (size_t)b * G1STRIDE + (size_t)o * 4096 + n0 + tn * 8;
            float v[8];
            #pragma unroll
            for (int j = 0; j < 8; ++j) v[j] = fmaxf(acc[i][j] + bi, 0.0f);
            *(float4*)(dst) = make_float4(v[0], v[1], v[2], v[3]);
            *(float4*)(dst + 4) = make_float4(v[4], v[5], v[6], v[7]);
        }
    } else {
        float* out = (float*)P0;
        #pragma unroll
        for (int i = 0; i < 8; ++i) {
            int o = m0 + tm * 8 + i;
            float bi = bias[o];
            size_t off = (size_t)b * XSTRIDE + (size_t)o * 4096 + n0 + tn * 8;
            float4 r0 = *(const float4*)(resid + off);
            float4 r1 = *(const float4*)(resid + off + 4);
            *(float4*)(out + off) = make_float4(acc[i][0] + bi + r0.x, acc[i][1] + bi + r0.y,
                                                acc[i][2] + bi + r0.z, acc[i][3] + bi + r0.w);
            *(float4*)(out + off + 4) = make_float4(acc[i][4] + bi + r1.x, acc[i][5] + bi + r1.y,
                                                    acc[i][6] + bi + r1.z, acc[i][7] + bi + r1.w);
        }
    }
}

// ---------------------------------------------------------------------------
// gate2 (exact fp32 path — trunc(tau*32) is discrete, do not perturb).
// ---------------------------------------------------------------------------
__global__ __launch_bounds__(64)
void gate2_kernel(const float* __restrict__ G1, const float* __restrict__ w2,
                  const float* __restrict__ b2, int* __restrict__ KD)
{
    const int b = blockIdx.y;
    const int n = blockIdx.x * 64 + threadIdx.x;
    const float* g = G1 + (size_t)b * G1STRIDE + n;
    float z = b2[0];
    #pragma unroll 8
    for (int c = 0; c < 128; ++c) z += w2[c] * g[(size_t)c * 4096];
    float tau = 1.0f / (1.0f + expf(-z));
    int kd = (int)(tau * 32.0f);
    kd = min(32, max(4, kd));
    KD[b * 4096 + n] = kd;
}

// ---------------------------------------------------------------------------
// compute 64x32 score block (cb half) into the slab — shared by both passes,
// so pass-2 scores are bit-identical to pass-1 (same MFMA chain).
// ---------------------------------------------------------------------------
__device__ __forceinline__ void score_block(
    const f16* __restrict__ kh_t, const f16* __restrict__ kl_t, int cb,
    const f16x8 ah[2][4], const f16x8 al[2][4],
    float* __restrict__ Ss, int ln, int g)
{
    #pragma unroll
    for (int rb = 0; rb < 2; ++rb) {
        f32x16 acc, accL;
        #pragma unroll
        for (int r = 0; r < 16; ++r) { acc[r] = 0.0f; accL[r] = 0.0f; }
        #pragma unroll
        for (int s = 0; s < 4; ++s) {
            f16x8 bh = *(const f16x8*)(kh_t + (size_t)(cb * 32 + ln) * 64 + s * 16 + g * 8);
            f16x8 bl = *(const f16x8*)(kl_t + (size_t)(cb * 32 + ln) * 64 + s * 16 + g * 8);
            acc  = __builtin_amdgcn_mfma_f32_32x32x16_f16(ah[rb][s], bh, acc,  0, 0, 0);
            accL = __builtin_amdgcn_mfma_f32_32x32x16_f16(al[rb][s], bh, accL, 0, 0, 0);
            accL = __builtin_amdgcn_mfma_f32_32x32x16_f16(ah[rb][s], bl, accL, 0, 0, 0);
        }
        // C layout: row=(r&3)+8*(r>>2)+4g, col=ln (verified m74/m101)
        #pragma unroll
        for (int r = 0; r < 16; ++r) {
            int riw = rb * 32 + (r & 3) + 8 * (r >> 2) + 4 * g;
            Ss[riw * 34 + ln] = acc[r] + accL[r] * (1.0f / 4096.0f);
        }
    }
}

// ---------------------------------------------------------------------------
// select v3 (R9): two-pass, spill-free. One wave/block, grid (128,8,2).
// Pass 1: values-only top-kd (L[32] regs, 3-op/slot insert, lagged per-block
//   thr refresh) -> exact theta = kd-th largest of this half + cntGT.
// Pass 2: recompute scores (bit-identical), append (val,idx) of the kd
//   qualifying candidates (c>theta all; c==theta first kd-cntGT in j-order)
//   straight to CV/CI in global — unsorted; merge_kernel sorts.
// amdgpu_waves_per_eu(2,2) pins the allocator at 256-reg/2-wave (R8: compiler
// chose 128 regs + spill despite launch_bounds min).
// ---------------------------------------------------------------------------
__global__ __launch_bounds__(64)
__attribute__((amdgpu_waves_per_eu(2, 2)))
void select_kernel(const f16* __restrict__ QH, const f16* __restrict__ QL,
                   const f16* __restrict__ KH, const f16* __restrict__ KL,
                   const int* __restrict__ KD,
                   float* __restrict__ CV, u16* __restrict__ CI)
{
    const int qt = blockIdx.x >> 1;     // 64-row group
    const int hf = blockIdx.x & 1;      // key half
    const int h = blockIdx.y, b = blockIdx.z;
    const size_t base = (size_t)((b * 8 + h) * 4096) * 64;
    const int lane = threadIdx.x;       // 0..63
    const int ln = lane & 31, g = lane >> 5;
    const int nw = qt * 64;
    const int k0base = hf * 2048;

    const int kd = KD[b * 4096 + nw + lane];
    const int kdm1 = kd - 1;

    __shared__ float Ss[64 * 34];       // 64 rows x 32 cols, stride 34

    // resident Q frags: A[m=ln][k=16s+8g+j]
    f16x8 ah[2][4], al[2][4];
    #pragma unroll
    for (int rb = 0; rb < 2; ++rb) {
        const f16* ph = QH + base + (size_t)(nw + rb * 32 + ln) * 64 + g * 8;
        const f16* pl = QL + base + (size_t)(nw + rb * 32 + ln) * 64 + g * 8;
        #pragma unroll
        for (int s = 0; s < 4; ++s) {
            ah[rb][s] = *(const f16x8*)(ph + s * 16);
            al[rb][s] = *(const f16x8*)(pl + s * 16);
        }
    }

    const float INF = __builtin_inff();
    const float* srow = &Ss[lane * 34];

    // ================= pass 1: values-only top-kd =================
    float L[32];
    #pragma unroll
    for (int r = 0; r < 32; ++r) L[r] = -INF;
    float thr = -INF;                    // lagged L[kd-1] (refreshed per block)

    for (int t = 0; t < 32; ++t) {
        const f16* kh_t = KH + base + (size_t)(k0base + t * 64) * 64;
        const f16* kl_t = KL + base + (size_t)(k0base + t * 64) * 64;
        #pragma unroll
        for (int cb = 0; cb < 2; ++cb) {
            score_block(kh_t, kl_t, cb, ah, al, Ss, ln, g);

            u32 m = 0;
            #pragma unroll
            for (int q = 0; q < 16; ++q) {
                float2 v = *(const float2*)(srow + 2 * q);
                m |= (v.x > thr) ? (1u << (2 * q)) : 0u;
                m |= (v.y > thr) ? (1u << (2 * q + 1)) : 0u;
            }
            while (__ballot(m != 0u)) {
                bool act = (m != 0u);
                int j = __builtin_ctz(m ? m : 1u);
                float c = act ? srow[j] : 0.0f;
                m &= (m - 1u);
                if (act && c > thr) {
                    #pragma unroll
                    for (int r = 31; r >= 1; --r) {
                        bool gp = c > L[r - 1];
                        bool gc = c > L[r];
                        L[r] = gp ? L[r - 1] : (gc ? c : L[r]);
                    }
                    if (c > L[0]) L[0] = c;
                }
            }
            // lagged thr refresh: thr = L[kd-1] (stale gate only over-admits,
            // slots < kd stay exact)
            {
                float th = L[31];
                #pragma unroll
                for (int r = 30; r >= 0; --r) th = (kdm1 == r) ? L[r] : th;
                thr = th;
            }
        }
    }
    const float theta = thr;             // exact kd-th largest of this half
    int cntGT = 0;
    #pragma unroll
    for (int r = 0; r < 32; ++r) cntGT += ((r < kd) && (L[r] > theta)) ? 1 : 0;
    const int eqNeed = kd - cntGT;

    // ================= pass 2: capture indices =================
    const size_t crow = (size_t)((b * 8 + h) * 4096 + nw + lane);
    float* cvp = CV + crow * 64 + hf * 32;
    u16*   cip = CI + crow * 64 + hf * 32;
    int cnt = 0, eqc = 0;

    for (int t = 0; t < 32; ++t) {
        const f16* kh_t = KH + base + (size_t)(k0base + t * 64) * 64;
        const f16* kl_t = KL + base + (size_t)(k0base + t * 64) * 64;
        #pragma unroll
        for (int cb = 0; cb < 2; ++cb) {
            score_block(kh_t, kl_t, cb, ah, al, Ss, ln, g);

            u32 m = 0;
            #pragma unroll
            for (int q = 0; q < 16; ++q) {
                float2 v = *(const float2*)(srow + 2 * q);
                m |= (v.x >= theta) ? (1u << (2 * q)) : 0u;
                m |= (v.y >= theta) ? (1u << (2 * q + 1)) : 0u;
            }
            const int jbase = k0base + t * 64 + cb * 32;
            while (__ballot(m != 0u)) {
                bool act = (m != 0u);
                int j = __builtin_ctz(m ? m : 1u);
                float c = act ? srow[j] : 0.0f;
                m &= (m - 1u);
                if (act) {
                    bool isGT = c > theta;
                    bool doA = (isGT || eqc < eqNeed) && cnt < 32;
                    if (doA) {
                        cvp[cnt] = c;
                        cip[cnt] = (u16)(jbase + j);
                        cnt++;
                        if (!isGT) eqc++;
                    }
                }
            }
        }
    }
}

// ---------------------------------------------------------------------------
// merge v2 (R9): per-row register sort-insert over the <=64 unsorted
// candidates (half0 slots then half1, each j-ascending => equal values land
// earliest-index-first with strict >; NaN filler never inserts), then
// softmax in rank order + V gather + O write. One thread per row.
// ---------------------------------------------------------------------------
__global__ __launch_bounds__(64)
void merge_kernel(const float* __restrict__ CV, const u16* __restrict__ CI,
                  const int* __restrict__ KD, const f16* __restrict__ VB,
                  float* __restrict__ O0, float* __restrict__ O1)
{
    const int tid = threadIdx.x;
    const size_t R0 = (size_t)blockIdx.x * 64;

    __shared__ float Lv[64][66];
    __shared__ u16   Li[64][66];
    __shared__ float Mv[64][34];
    __shared__ u16   Mi[64][34];

    for (int i = 0; i < 64; ++i) {       // coalesced stage
        Lv[i][tid] = CV[(R0 + i) * 64 + tid];
        Li[i][tid] = CI[(R0 + i) * 64 + tid];
    }
    __syncthreads();

    const int myR = (int)R0 + tid;       // = (b*8+h)*4096 + n
    const int b = myR >> 15, n = myR & 4095, h = (myR >> 12) & 7;
    const int kd = KD[b * 4096 + n];

    const float INF = __builtin_inff();
    float L[32]; int I[32];
    #pragma unroll
    for (int r = 0; r < 32; ++r) { L[r] = -INF; I[r] = 0; }

    for (int i = 0; i < 64; ++i) {
        float c = Lv[tid][i];            // NaN filler: all compares false
        int  ix = Li[tid][i];
        if (c > L[31]) {
            #pragma unroll
            for (int r = 31; r >= 1; --r) {
                bool gp = c > L[r - 1];
                bool gc = c > L[r];
                L[r] = gp ? L[r - 1] : (gc ? c : L[r]);
                I[r] = gp ? I[r - 1] : (gc ? ix : I[r]);
            }
            if (c > L[0]) { I[0] = ix; L[0] = c; }
        }
    }

    // park sorted list (register->LDS) for dynamic-index softmax/gather
    #pragma unroll
    for (int r = 0; r < 32; ++r) { Mv[tid][r] = L[r]; Mi[tid][r] = (u16)I[r]; }

    const float mx = Mv[tid][0];
    float sum = 0.0f;
    for (int k = 0; k < kd; ++k) {       // rank order, matches reference
        float e = expf(Mv[tid][k] - mx);
        Mv[tid][k] = e;
        sum += e;
    }
    const float inv = 1.0f / sum;

    float o[64];
    #pragma unroll
    for (int d = 0; d < 64; ++d) o[d] = 0.0f;
    const size_t vbase = (size_t)((b * 8 + h)) * 4096 * 64;
    for (int k = 0; k < kd; ++k) {
        float wgt = Mv[tid][k] * inv;
        const f16* vp = VB + vbase + (size_t)Mi[tid][k] * 64;
        #pragma unroll
        for (int part = 0; part < 8; ++part) {
            f16x8 vv = *(const f16x8*)(vp + part * 8);
            #pragma unroll
            for (int e2 = 0; e2 < 8; ++e2) o[part * 8 + e2] += wgt * (float)vv[e2];
        }
    }

    __syncthreads();                     // done reading Lv lists
    #pragma unroll
    for (int q = 0; q < 32; ++q)
        *(float2*)(&Lv[tid][2 * q]) = make_float2(o[2 * q], o[2 * q + 1]);
    __syncthreads();
    for (int i = 0; i < 64; ++i) {       // coalesced O store
        float val = Lv[i][tid];
        size_t R = R0 + i;
        if (tid < 32) O0[R * 32 + tid] = val;
        else          O1[R * 32 + (tid - 32)] = val;
    }
}

// ---------------------------------------------------------------------------
extern "C" void kernel_launch(void* const* d_in, const int* in_sizes, int n_in,
                              void* d_out, int out_size, void* d_ws, size_t ws_size,
                              hipStream_t stream)
{
    const float* x      = (const float*)d_in[0];
    const float* w_qkv  = (const float*)d_in[1];
    const float* w_proj = (const float*)d_in[2];
    const float* b_proj = (const float*)d_in[3];
    const float* w_g1   = (const float*)d_in[4];
    const float* b_g1   = (const float*)d_in[5];
    const float* w_g2   = (const float*)d_in[6];
    const float* b_g2   = (const float*)d_in[7];
    float* out = (float*)d_out;
    float* ws  = (float*)d_ws;

    f16* QH = (f16*)(ws + WS_QH);
    f16* QL = (f16*)(ws + WS_QL);
    f16* KH = (f16*)(ws + WS_KH);
    f16* KL = (f16*)(ws + WS_KL);
    f16* VB = (f16*)(ws + WS_VB);
    float* G1 = ws + WS_G1;
    int*   KD = (int*)(ws + WS_KD);
    u16*   CI = (u16*)(ws + WS_CI);
    float* CV = out;          // d_out as CV scratch (NaN-filled; proj overwrites later)
    float* O0 = (float*)QH;   // overlay: O replaces Q hi/lo (select done before merge)
    float* O1 = (float*)QL;

    // CV = NaN filler (0xFF bytes): unwritten slots never insert in merge
    hipMemsetAsync(CV, 0xFF, (size_t)out_size * sizeof(float), stream);

    gemm_kernel<0><<<dim3(32, 12, 2), 256, 0, stream>>>(
        w_qkv, x, nullptr, nullptr, QH, QL, KH, KL, VB);
    gemm_kernel<1><<<dim3(32, 1, 2), 256, 0, stream>>>(
        w_g1, x, b_g1, nullptr, G1, nullptr, nullptr, nullptr, nullptr);
    gate2_kernel<<<dim3(64, 2), 64, 0, stream>>>(G1, w_g2, b_g2, KD);
    select_kernel<<<dim3(128, 8, 2), 64, 0, stream>>>(QH, QL, KH, KL, KD, CV, CI);
    merge_kernel<<<dim3(1024), 64, 0, stream>>>(CV, CI, KD, VB, O0, O1);
    gemm_kernel<2><<<dim3(32, 4, 2), 256, 0, stream>>>(
        w_proj, nullptr, b_proj, x, out, O0, O1, nullptr, nullptr);
}